// Round 6
// baseline (353.047 us; speedup 1.0000x reference)
//
#include <hip/hip_runtime.h>
#include <math.h>

#define NN 100000
#define NE 1600000
#define NG 2048
#define NBUK 391     // ceil(NN/256) dst-buckets, bucket = dst >> 8
#define SLOT 6144    // per-bucket capacity: mean 4096 + 32 sigma
#define CHUNK 8192   // edges per bin block
#define BINB 196     // bin blocks (NE/CHUNK = 195.3 -> 196)
#define MT_ALL 6250  // m-tiles for gemm1 (NN/16)
#define MT_SPLIT 3456// gemm1a covers [0,MT_SPLIT), gemm1b the rest
#define GA 520       // gemm1a blocks (2080 waves)
#define GB 440       // gemm1b blocks (1760 waves)

typedef __attribute__((ext_vector_type(8))) short short8;
typedef __attribute__((ext_vector_type(8))) __bf16 bf16x8;
typedef __attribute__((ext_vector_type(4))) float f32x4;
typedef __attribute__((ext_vector_type(2))) float f32x2;
typedef __attribute__((ext_vector_type(4))) unsigned int uint4_;

__device__ __forceinline__ unsigned short f2bf(float f) {       // RNE, finite inputs
    unsigned int u = __float_as_uint(f);
    return (unsigned short)((u + 0x7FFFu + ((u >> 16) & 1u)) >> 16);
}
__device__ __forceinline__ float bf2f(unsigned short s) {
    return __uint_as_float(((unsigned int)s) << 16);
}
__device__ __forceinline__ unsigned char f2fp8(float v) {       // HW cvt, e4m3fn
    int p = __builtin_amdgcn_cvt_pk_fp8_f32(v, v, 0, false);
    return (unsigned char)(p & 0xFF);
}

// ---------------- setup: w2bf (transposed) + grange + gcnt/deg zero ----------------
__global__ __launch_bounds__(256) void setup_kernel(const float* __restrict__ W1,
                                                    const float* __restrict__ W2,
                                                    const float* __restrict__ W3,
                                                    unsigned short* __restrict__ Wb1t,
                                                    unsigned short* __restrict__ Wb2t,
                                                    unsigned short* __restrict__ Wb3t,
                                                    const int* __restrict__ batch,
                                                    int* __restrict__ gstart,
                                                    int* __restrict__ gcnt,
                                                    int* __restrict__ deg) {
    const int bid = blockIdx.x, t = threadIdx.x;
    if (bid < 104) {                                  // weight cvt+transpose (26624 elems)
        int i = bid * 256 + t;
        if (i < 16384) {                              // W1: 128x128
            int k = i >> 7, c = i & 127;
            Wb1t[c * 128 + k] = f2bf(W1[i]);
        } else if (i < 24576) {                       // W2: 128x64
            int j = i - 16384; int k = j >> 6, c = j & 63;
            Wb2t[c * 128 + k] = f2bf(W2[j]);
        } else if (i < 26624) {                       // W3: 64x32
            int j = i - 24576; int k = j >> 5, c = j & 31;
            Wb3t[c * 64 + k] = f2bf(W3[j]);
        }
    } else if (bid < 113) {                           // grange (batch sorted)
        int g = (bid - 104) * 256 + t;
        if (g > NG) return;
        if (g == NG) { gstart[g] = NN; return; }
        int lo = 0, hi = NN;
        while (lo < hi) { int mid = (lo + hi) >> 1; if (batch[mid] < g) lo = mid + 1; else hi = mid; }
        gstart[g] = lo;
    } else if (bid == 113) {                          // zero gcnt (512 ints)
        gcnt[t] = 0; gcnt[t + 256] = 0;
    } else {                                          // zero deg (391 blocks)
        int n = (bid - 114) * 256 + t;
        if (n < NN) deg[n] = 0;
    }
}

// ---------------- R18: per-node degree via global atomics (breaks dinv dependency) ----------------
// Exact integer counts -> rsqrtf(deg+1) is bit-identical to the csr2a-derived dinv.
__global__ __launch_bounds__(256) void deg_kernel(const int* __restrict__ dst,
                                                  int* __restrict__ deg) {
    int i = blockIdx.x * 256 + threadIdx.x;
    const int stride = gridDim.x * 256;
    for (; i < NE; i += stride) atomicAdd(&deg[dst[i]], 1);
}

// ---------------- MFMA GEMM body ----------------
// Layouts [m89-verified]: A: m=lane&15, k=quad*8+j ; B: n=lane&15, k=quad*8+j ;
//                         C/D: col=lane&15, row=quad*4+reg.
// USE_DEG: row scale computed inline as rsqrtf(deg[row]+1) (gemm1 runs before csr2afill).
template<int FIN, int FOUT, bool RELU_IN, bool A_BF16, bool OUT_FP8, bool USE_DEG>
__device__ __forceinline__ void gemm_body(const void* __restrict__ in_,
                                          const unsigned short* __restrict__ Wbt,
                                          const float* __restrict__ dinv,
                                          const int* __restrict__ deg,
                                          void* __restrict__ out,
                                          int mt0, int mt1, int nwaves, int wid, int lane) {
    constexpr int NT = FOUT / 16;
    constexpr int KS = FIN / 32;
    const int m16  = lane & 15;
    const int quad = lane >> 4;
    const int koff = quad * 8;

    short8 bfrag[NT][KS];
#pragma unroll
    for (int nt = 0; nt < NT; ++nt) {
        const unsigned short* wcol = Wbt + (size_t)(m16 + nt * 16) * FIN + koff;
#pragma unroll
        for (int ks = 0; ks < KS; ++ks)
            bfrag[nt][ks] = *(const short8*)(wcol + ks * 32);
    }

    int mt = mt0 + wid;
    if (mt >= mt1) return;

    short8 curB[KS], nxtB[KS];
    f32x4  curF[KS][2], nxtF[KS][2];

    auto load_raw = [&](int m, short8* rb, f32x4 (*rf)[2]) {
        const int row = m * 16 + m16;
        if (A_BF16) {
            const unsigned short* A = (const unsigned short*)in_ + (size_t)row * FIN + koff;
#pragma unroll
            for (int ks = 0; ks < KS; ++ks) rb[ks] = *(const short8*)(A + ks * 32);
        } else {
            const float* A = (const float*)in_ + (size_t)row * FIN + koff;
#pragma unroll
            for (int ks = 0; ks < KS; ++ks) {
                rf[ks][0] = *(const f32x4*)(A + ks * 32);
                rf[ks][1] = *(const f32x4*)(A + ks * 32 + 4);
            }
        }
    };

    load_raw(mt, curB, curF);
    while (true) {
        const int mtn = mt + nwaves;
        const bool have_next = (mtn < mt1);
        if (have_next) load_raw(mtn, nxtB, nxtF);   // in flight across the MFMAs below

        short8 afrag[KS];
        if (A_BF16) {
#pragma unroll
            for (int ks = 0; ks < KS; ++ks) {
                short8 a = curB[ks];
                if (RELU_IN) {
#pragma unroll
                    for (int j = 0; j < 8; ++j)
                        a[j] = (short)(((unsigned short)a[j] & 0x8000u) ? 0 : (unsigned short)a[j]);
                }
                afrag[ks] = a;
            }
        } else {
#pragma unroll
            for (int ks = 0; ks < KS; ++ks) {
#pragma unroll
                for (int j = 0; j < 4; ++j) {
                    float a0 = curF[ks][0][j], a1 = curF[ks][1][j];
                    if (RELU_IN) { a0 = fmaxf(a0, 0.f); a1 = fmaxf(a1, 0.f); }
                    afrag[ks][j]     = (short)f2bf(a0);
                    afrag[ks][j + 4] = (short)f2bf(a1);
                }
            }
        }

        f32x4 acc[NT];
#pragma unroll
        for (int nt = 0; nt < NT; ++nt) acc[nt] = (f32x4){0.f, 0.f, 0.f, 0.f};
#pragma unroll
        for (int nt = 0; nt < NT; ++nt)
#pragma unroll
            for (int ks = 0; ks < KS; ++ks)
                acc[nt] = __builtin_amdgcn_mfma_f32_16x16x32_bf16(
                    __builtin_bit_cast(bf16x8, afrag[ks]),
                    __builtin_bit_cast(bf16x8, bfrag[nt][ks]), acc[nt], 0, 0, 0);

        float dv[4];
#pragma unroll
        for (int r = 0; r < 4; ++r) {
            const int row = mt * 16 + quad * 4 + r;
            dv[r] = USE_DEG ? rsqrtf((float)deg[row] + 1.0f) : dinv[row];
        }
#pragma unroll
        for (int nt = 0; nt < NT; ++nt) {
            const int col = m16 + nt * 16;
#pragma unroll
            for (int r = 0; r < 4; ++r) {
                int orow = mt * 16 + quad * 4 + r;
                float v = acc[nt][r] * dv[r];
                if (OUT_FP8)
                    ((unsigned char*)out)[(size_t)orow * FOUT + col] = f2fp8(v);
                else
                    ((unsigned short*)out)[(size_t)orow * FOUT + col] = f2bf(v);
            }
        }

        if (!have_next) break;
#pragma unroll
        for (int ks = 0; ks < KS; ++ks) {
            curB[ks] = nxtB[ks];
            curF[ks][0] = nxtF[ks][0];
            curF[ks][1] = nxtF[ks][1];
        }
        mt = mtn;
    }
}

// ---------------- fused: edge binning (blocks 0..195) || gemm1a (rest) ----------------
__global__ __launch_bounds__(256, 2) void bin_gemm1_kernel(const int* __restrict__ src,
                                                           const int* __restrict__ dst,
                                                           int* __restrict__ gcnt,
                                                           int* __restrict__ bucket_data,
                                                           const float* __restrict__ x,
                                                           const unsigned short* __restrict__ Wb1t,
                                                           const int* __restrict__ deg,
                                                           unsigned char* __restrict__ hs) {
    __shared__ int cnt[512];                 // padded scan array
    __shared__ int offs[NBUK];
    __shared__ int cnt2[NBUK];
    __shared__ int gb[NBUK];
    __shared__ int packB[CHUNK];
    __shared__ unsigned short bktB[CHUNK];
    const int t = threadIdx.x;
    if (blockIdx.x < BINB) {
        const int E0 = blockIdx.x * CHUNK;
        const int valid = min(CHUNK, NE - E0);
        cnt[t] = 0; cnt[t + 256] = 0;
        for (int i = t; i < NBUK; i += 256) cnt2[i] = 0;
        __syncthreads();
        // A: count buckets
        for (int i = t; i < valid; i += 256)
            atomicAdd(&cnt[dst[E0 + i] >> 8], 1);
        __syncthreads();
        int o0 = cnt[t], o1 = cnt[t + 256];
        // B: inclusive Hillis-Steele scan over 512 (2 elems/thread)
        for (int off = 1; off < 512; off <<= 1) {
            int a0 = (t >= off) ? cnt[t - off] : 0;
            int a1 = (t + 256 >= off) ? cnt[t + 256 - off] : 0;
            __syncthreads();
            cnt[t] += a0; cnt[t + 256] += a1;
            __syncthreads();
        }
        if (t < NBUK)       { offs[t] = cnt[t] - o0;             gb[t] = o0 ? atomicAdd(&gcnt[t], o0) : 0; }
        if (t + 256 < NBUK) { offs[t + 256] = cnt[t + 256] - o1; gb[t + 256] = o1 ? atomicAdd(&gcnt[t + 256], o1) : 0; }
        __syncthreads();
        // C: re-read edges, place bucket-sorted into LDS
        for (int i = t; i < valid; i += 256) {
            int s = src[E0 + i], d = dst[E0 + i];
            int b = d >> 8;
            int pos = offs[b] + atomicAdd(&cnt2[b], 1);
            packB[pos] = (s << 8) | (d & 255);
            bktB[pos] = (unsigned short)b;
        }
        __syncthreads();
        // D: contiguous-per-bucket append to global streams
        for (int i = t; i < valid; i += 256) {
            int b = bktB[i];
            int idx = gb[b] + (i - offs[b]);
            if (idx < SLOT) bucket_data[b * SLOT + idx] = packB[i];
        }
    } else {
        const int wid = ((blockIdx.x - BINB) * 256 + t) >> 6;
        gemm_body<128, 128, false, false, true, true>(x, Wb1t, nullptr, deg, hs,
                                                      0, MT_SPLIT, GA * 4, wid, t & 63);
    }
}

// ---------------- fused: csr2a+fill merged (blocks 0..390) || gemm1b (rest) ----------------
// Merged per bucket: cross-bucket scan -> base; per-node counts -> rowptr/dinv;
// then re-read bucket and fine-scatter csr_src using the in-LDS rowptr (offs).
__global__ __launch_bounds__(256, 2) void csr2afill_gemm1_kernel(const int* __restrict__ gcnt,
                                                                 const int* __restrict__ bucket_data,
                                                                 float* __restrict__ dinv,
                                                                 int* __restrict__ rowptr,
                                                                 int* __restrict__ csr_src,
                                                                 const float* __restrict__ x,
                                                                 const unsigned short* __restrict__ Wb1t,
                                                                 const int* __restrict__ deg,
                                                                 unsigned char* __restrict__ hs) {
    __shared__ int bs[512];
    __shared__ int counts[256];
    __shared__ int offs[256];
    __shared__ int cnt2[256];
    __shared__ int base_sh;
    const int t = threadIdx.x;
    if (blockIdx.x < NBUK) {
        const int b = blockIdx.x;
        // inline exclusive scan of min(gcnt,SLOT) over all buckets (redundant per block)
        bs[t] = (t < NBUK) ? min(gcnt[t], SLOT) : 0;
        bs[t + 256] = (t + 256 < NBUK) ? min(gcnt[t + 256], SLOT) : 0;
        counts[t] = 0;
        __syncthreads();
        for (int off = 1; off < 512; off <<= 1) {
            int a0 = (t >= off) ? bs[t - off] : 0;
            int a1 = (t + 256 >= off) ? bs[t + 256 - off] : 0;
            __syncthreads();
            bs[t] += a0; bs[t + 256] += a1;
            __syncthreads();
        }
        if (t == 0) base_sh = bs[b] - min(gcnt[b], SLOT);   // exclusive base
        __syncthreads();
        const int cb = min(gcnt[b], SLOT);
        const int* bd = bucket_data + b * SLOT;
        for (int i = t; i < cb; i += 256) atomicAdd(&counts[bd[i] & 255], 1);
        __syncthreads();
        int c = counts[t];
        for (int off = 1; off < 256; off <<= 1) {
            int a = (t >= off) ? counts[t - off] : 0;
            __syncthreads();
            counts[t] += a;
            __syncthreads();
        }
        int rp = base_sh + counts[t] - c;       // rowptr for node b*256+t
        int node = b * 256 + t;
        if (node < NN) {
            dinv[node] = rsqrtf((float)c + 1.0f);
            rowptr[node] = rp;
        }
        offs[t] = rp;
        cnt2[t] = 0;
        __syncthreads();
        // fine-scatter csr_src (same as old fill path, rowptr from LDS)
        for (int i = t; i < cb; i += 256) {
            int p = bd[i];
            int local = p & 255;
            int pos = atomicAdd(&cnt2[local], 1);
            csr_src[offs[local] + pos] = p >> 8;   // p>=0, arith shift ok
        }
        if (b == NBUK - 1 && t == 0) rowptr[NN] = NE;
    } else {
        const int wid = ((blockIdx.x - NBUK) * 256 + t) >> 6;
        gemm_body<128, 128, false, false, true, true>(x, Wb1t, nullptr, deg, hs,
                                                      MT_SPLIT, MT_ALL, GB * 4, wid, t & 63);
    }
}

// ---------------- fused agg(FIN fp8 gather) + gemm(FIN->FOUT) ----------------
// R16 structure (natural node order; R15/R17 showed sorting is null-to-negative).
// LDS XOR swizzle (byte ^= (row&7)<<4) fixes the 16-way ds_read_b128 conflict.
// Gather pinned at ~6.25 B/cyc/CU (MSHR x L3-latency ceiling) — R13/R15/R16/R17 probes.
template<int FIN, int FOUT, bool OUT_FP8>
__global__ __launch_bounds__(256) void agg_gemm_kernel(const int* __restrict__ rowptr,
                                                       const int* __restrict__ csr_src,
                                                       const unsigned char* __restrict__ hs,
                                                       const float* __restrict__ dinv,
                                                       const float* __restrict__ bias,
                                                       const unsigned short* __restrict__ Wbt,
                                                       void* __restrict__ out, int N) {
    constexpr int TPN  = FIN / 16;          // lanes per node (16 fp8 = 16 B each)
    constexpr int NPB  = 256 / TPN;         // nodes per block (32 or 64)
    constexpr int NTILE = NPB / 16;         // 16-row m-tiles per block (2 or 4)
    constexpr int WPT  = 4 / NTILE;         // waves per tile (2 or 1)
    constexpr int NT   = FOUT / (16 * WPT); // col-tiles per wave (2 in both cases)
    constexpr int KS   = FIN / 32;
    __shared__ unsigned short lag[NPB * FIN];   // XOR-swizzled rows

    const int t = threadIdx.x;
    const int nb = blockIdx.x;
    const int n = nb * NPB + t / TPN;

    // ---- phase 1: gather-aggregate (identical math/order to standalone agg8) ----
    if (n < N) {
        const uint4_* hp = (const uint4_*)hs;
        const int lanep = t % TPN;
        const int lrow  = t / TPN;
        const int rstride = FIN / 16;
        const int c16 = lanep * 16;
        int row = rowptr[n], end = rowptr[n + 1];
        float acc[16];
        {
            uint4_ u = hp[(size_t)n * rstride + lanep];   // self term
#pragma unroll
            for (int w = 0; w < 4; ++w) {
                f32x2 lo = __builtin_amdgcn_cvt_pk_f32_fp8(u[w], false);
                f32x2 hi = __builtin_amdgcn_cvt_pk_f32_fp8(u[w], true);
                acc[w * 4 + 0] = lo[0]; acc[w * 4 + 1] = lo[1];
                acc[w * 4 + 2] = hi[0]; acc[w * 4 + 3] = hi[1];
            }
        }
        int j = row;
        for (; j + 4 <= end; j += 4) {
            int s0 = csr_src[j], s1 = csr_src[j + 1], s2 = csr_src[j + 2], s3 = csr_src[j + 3];
            uint4_ u0 = hp[(size_t)s0 * rstride + lanep];
            uint4_ u1 = hp[(size_t)s1 * rstride + lanep];
            uint4_ u2 = hp[(size_t)s2 * rstride + lanep];
            uint4_ u3 = hp[(size_t)s3 * rstride + lanep];
#pragma unroll
            for (int w = 0; w < 4; ++w) {
                f32x2 a0 = __builtin_amdgcn_cvt_pk_f32_fp8(u0[w], false);
                f32x2 b0 = __builtin_amdgcn_cvt_pk_f32_fp8(u0[w], true);
                f32x2 a1 = __builtin_amdgcn_cvt_pk_f32_fp8(u1[w], false);
                f32x2 b1 = __builtin_amdgcn_cvt_pk_f32_fp8(u1[w], true);
                f32x2 a2 = __builtin_amdgcn_cvt_pk_f32_fp8(u2[w], false);
                f32x2 b2 = __builtin_amdgcn_cvt_pk_f32_fp8(u2[w], true);
                f32x2 a3 = __builtin_amdgcn_cvt_pk_f32_fp8(u3[w], false);
                f32x2 b3 = __builtin_amdgcn_cvt_pk_f32_fp8(u3[w], true);
                acc[w * 4 + 0] += (a0[0] + a1[0]) + (a2[0] + a3[0]);
                acc[w * 4 + 1] += (a0[1] + a1[1]) + (a2[1] + a3[1]);
                acc[w * 4 + 2] += (b0[0] + b1[0]) + (b2[0] + b3[0]);
                acc[w * 4 + 3] += (b0[1] + b1[1]) + (b2[1] + b3[1]);
            }
        }
        for (; j < end; ++j) {
            uint4_ u = hp[(size_t)csr_src[j] * rstride + lanep];
#pragma unroll
            for (int w = 0; w < 4; ++w) {
                f32x2 lo = __builtin_amdgcn_cvt_pk_f32_fp8(u[w], false);
                f32x2 hi = __builtin_amdgcn_cvt_pk_f32_fp8(u[w], true);
                acc[w * 4 + 0] += lo[0]; acc[w * 4 + 1] += lo[1];
                acc[w * 4 + 2] += hi[0]; acc[w * 4 + 3] += hi[1];
            }
        }
        float c = dinv[n];
        short8 o0, o1;
#pragma unroll
        for (int k = 0; k < 8; ++k) {
            unsigned short s0 = f2bf(fmaf(acc[k],     c, bias[c16 + k]));
            unsigned short s1 = f2bf(fmaf(acc[k + 8], c, bias[c16 + 8 + k]));
            o0[k] = (short)((s0 & 0x8000u) ? 0 : s0);   // relu folded (== gemm's bf16 relu)
            o1[k] = (short)((s1 & 0x8000u) ? 0 : s1);
        }
        const unsigned int bofs = (unsigned)(lrow * (FIN * 2) + c16 * 2);
        const unsigned int msk  = (unsigned)((lrow & 7) << 4);
        *(short8*)((char*)lag + (bofs ^ msk)) = o0;
        *(short8*)((char*)lag + ((bofs + 16) ^ msk)) = o1;
    }
    __syncthreads();

    // ---- phase 2: GEMM m-tiles of this block's rows from LDS (swizzled reads) ----
    const int lane = t & 63, wv = t >> 6;
    const int m16 = lane & 15, quad = lane >> 4;
    const int tile = wv / WPT, ch = wv - tile * WPT;
    const int colb = ch * NT * 16;

    short8 bfrag[NT][KS];
#pragma unroll
    for (int nt = 0; nt < NT; ++nt) {
        const unsigned short* wcol = Wbt + (size_t)(colb + nt * 16 + m16) * FIN + quad * 8;
#pragma unroll
        for (int ks = 0; ks < KS; ++ks)
            bfrag[nt][ks] = *(const short8*)(wcol + ks * 32);
    }
    short8 afrag[KS];
    const int arow = tile * 16 + m16;
    const unsigned int abase = (unsigned)(arow * (FIN * 2) + quad * 16);
    const unsigned int am    = (unsigned)((arow & 7) << 4);
#pragma unroll
    for (int ks = 0; ks < KS; ++ks)
        afrag[ks] = *(const short8*)((char*)lag + ((abase + (unsigned)(ks * 64)) ^ am));

    f32x4 acc2[NT];
#pragma unroll
    for (int nt = 0; nt < NT; ++nt) acc2[nt] = (f32x4){0.f, 0.f, 0.f, 0.f};
#pragma unroll
    for (int nt = 0; nt < NT; ++nt)
#pragma unroll
        for (int ks = 0; ks < KS; ++ks)
            acc2[nt] = __builtin_amdgcn_mfma_f32_16x16x32_bf16(
                __builtin_bit_cast(bf16x8, afrag[ks]),
                __builtin_bit_cast(bf16x8, bfrag[nt][ks]), acc2[nt], 0, 0, 0);

    const int rbase = nb * NPB + tile * 16 + quad * 4;
    float dv[4];
#pragma unroll
    for (int r = 0; r < 4; ++r) dv[r] = dinv[min(rbase + r, N - 1)];
#pragma unroll
    for (int nt = 0; nt < NT; ++nt) {
        const int col = colb + nt * 16 + m16;
#pragma unroll
        for (int r = 0; r < 4; ++r) {
            int orow = rbase + r;
            if (orow < N) {
                float v = acc2[nt][r] * dv[r];
                if (OUT_FP8)
                    ((unsigned char*)out)[(size_t)orow * FOUT + col] = f2fp8(v);
                else
                    ((unsigned short*)out)[(size_t)orow * FOUT + col] = f2bf(v);
            }
        }
    }
}

// ---------------- bf16 gather-aggregate (layer 3): fp32 out for pooling ----------------
__global__ __launch_bounds__(256) void agg3_kernel(const int* __restrict__ rowptr,
                                                   const int* __restrict__ csr_src,
                                                   const unsigned short* __restrict__ hs,
                                                   const float* __restrict__ dinv,
                                                   const float* __restrict__ b,
                                                   float* __restrict__ aggout, int N) {
    constexpr int F = 32, TPN = 4, NPB = 64;
    int n = blockIdx.x * NPB + threadIdx.x / TPN;
    int c8 = (threadIdx.x % TPN) * 8;
    if (n >= N) return;
    int row = rowptr[n], end = rowptr[n + 1];
    float acc[8];
    {
        short8 h = *(const short8*)(hs + (size_t)n * F + c8);   // self term
#pragma unroll
        for (int j = 0; j < 8; ++j) acc[j] = bf2f((unsigned short)h[j]);
    }
    int j = row;
    for (; j + 4 <= end; j += 4) {
        int s0 = csr_src[j], s1 = csr_src[j + 1], s2 = csr_src[j + 2], s3 = csr_src[j + 3];
        short8 h0 = *(const short8*)(hs + (size_t)s0 * F + c8);
        short8 h1 = *(const short8*)(hs + (size_t)s1 * F + c8);
        short8 h2 = *(const short8*)(hs + (size_t)s2 * F + c8);
        short8 h3 = *(const short8*)(hs + (size_t)s3 * F + c8);
#pragma unroll
        for (int k = 0; k < 8; ++k)
            acc[k] += (bf2f((unsigned short)h0[k]) + bf2f((unsigned short)h1[k])) +
                      (bf2f((unsigned short)h2[k]) + bf2f((unsigned short)h3[k]));
    }
    for (; j < end; ++j) {
        int s = csr_src[j];
        short8 h = *(const short8*)(hs + (size_t)s * F + c8);
#pragma unroll
        for (int k = 0; k < 8; ++k) acc[k] += bf2f((unsigned short)h[k]);
    }
    float c = dinv[n];
    f32x4 o0, o1;
#pragma unroll
    for (int k = 0; k < 4; ++k) {
        o0[k] = fmaf(acc[k], c, b[c8 + k]);
        o1[k] = fmaf(acc[k + 4], c, b[c8 + k + 4]);
    }
    float* of = aggout + (size_t)n * F + c8;
    *(f32x4*)of = o0;
    *(f32x4*)(of + 4) = o1;
}

// ---------------- pool: pooled[g,:] = mean of h rows in [gstart[g], gstart[g+1]) ----------------
__global__ __launch_bounds__(256) void pool2_kernel(const float* __restrict__ h,
                                                    const int* __restrict__ gstart,
                                                    float* __restrict__ pooled) {
    __shared__ float sm[256];
    int g = blockIdx.x;
    int s = gstart[g], e = gstart[g + 1];
    int f = threadIdx.x & 31, slot = threadIdx.x >> 5;
    float acc = 0.f;
    for (int n = s + slot; n < e; n += 8) acc += h[(size_t)n * 32 + f];
    sm[threadIdx.x] = acc;
    __syncthreads();
    if (threadIdx.x < 128) sm[threadIdx.x] += sm[threadIdx.x + 128];
    __syncthreads();
    if (threadIdx.x < 64) sm[threadIdx.x] += sm[threadIdx.x + 64];
    __syncthreads();
    if (threadIdx.x < 32) {
        float v = sm[threadIdx.x] + sm[threadIdx.x + 32];
        float cntf = fmaxf((float)(e - s), 1.0f);
        pooled[(size_t)g * 32 + f] = v / cntf;
    }
}

// ---------------- epilogue: logits, sigmoid, BCE mean ----------------
__global__ __launch_bounds__(256) void final_kernel(const float* __restrict__ pooled,
                                                    const float* __restrict__ Wl,
                                                    const float* __restrict__ bl,
                                                    const int* __restrict__ targets,
                                                    float* __restrict__ out) {
    __shared__ float red[256];
    float lsum = 0.0f;
    for (int g = threadIdx.x; g < NG; g += 256) {
        float acc = bl[0];
#pragma unroll
        for (int k = 0; k < 32; ++k)
            acc = fmaf(pooled[(size_t)g * 32 + k], Wl[k], acc);
        out[g] = 1.0f / (1.0f + expf(-acc));
        float y = (float)targets[g];
        lsum += fmaxf(acc, 0.0f) - acc * y + log1pf(expf(-fabsf(acc)));
    }
    red[threadIdx.x] = lsum;
    __syncthreads();
    for (int s = 128; s > 0; s >>= 1) {
        if (threadIdx.x < s) red[threadIdx.x] += red[threadIdx.x + s];
        __syncthreads();
    }
    if (threadIdx.x == 0) out[NG] = red[0] / (float)NG;
}

extern "C" void kernel_launch(void* const* d_in, const int* in_sizes, int n_in,
                              void* d_out, int out_size, void* d_ws, size_t ws_size,
                              hipStream_t stream) {
    const float* x       = (const float*)d_in[0];
    const int*   ei      = (const int*)d_in[1];
    const int*   batch   = (const int*)d_in[2];
    const int*   targets = (const int*)d_in[3];
    const float* W1 = (const float*)d_in[4];
    const float* b1 = (const float*)d_in[5];
    const float* W2 = (const float*)d_in[6];
    const float* b2 = (const float*)d_in[7];
    const float* W3 = (const float*)d_in[8];
    const float* b3 = (const float*)d_in[9];
    const float* Wl = (const float*)d_in[10];
    const float* bl = (const float*)d_in[11];
    float* out = (float*)d_out;
    char*  ws  = (char*)d_ws;

    const int* src = ei;
    const int* dst = ei + NE;

    // workspace layout (byte offsets, 512B aligned) — total ~68.3 MB
    float*          dinv    = (float*)(ws);                    //    400,384 B
    int*            rowptr  = (int*)(ws + 400384);             //    400,384 B (NN+1)
    int*            csr_src = (int*)(ws + 800768);             //  6,400,512 B
    unsigned short* Wb1t    = (unsigned short*)(ws + 7201280); //     32,768 B (transposed)
    unsigned short* Wb2t    = (unsigned short*)(ws + 7234048); //     16,384 B (transposed)
    unsigned short* Wb3t    = (unsigned short*)(ws + 7250432); //      4,096 B (transposed)
    int*            gstart  = (int*)(ws + 7254528);            //      8,704 B (NG+1)
    unsigned char*  hsbuf   = (unsigned char*)(ws + 7263232);  // 12.8 MB fp8/bf16 hs (layer1/3)
    int*            deg     = (int*)(ws + 20263424);           //    400,384 B (hsbuf slack)
    unsigned short* aggbuf  = (unsigned short*)(ws + 32863744);// 25,600,512 B (fp8 hs2 / fp32 agg3)
    float*          pooled  = (float*)(ws + 58464256);         //    262,144 B
    int*            bdata   = (int*)(ws + 58726400);           //  9,609,216 B (391*6144*4)
    int*            gcnt    = (int*)(ws + 68335616);           //      2,048 B

    // ---- setup (w2bf + grange + gcnt/deg zero) ----
    setup_kernel<<<505, 256, 0, stream>>>(W1, W2, W3, Wb1t, Wb2t, Wb3t, batch, gstart, gcnt, deg);

    // ---- degree via atomics (breaks the dinv->gemm1 dependency) ----
    deg_kernel<<<400, 256, 0, stream>>>(dst, deg);

    // ---- bin || gemm1a (m-tiles [0, MT_SPLIT)) ----
    bin_gemm1_kernel<<<BINB + GA, 256, 0, stream>>>(src, dst, gcnt, bdata, x, Wb1t, deg, hsbuf);

    // ---- csr2a+fill merged || gemm1b (m-tiles [MT_SPLIT, MT_ALL)) ----
    csr2afill_gemm1_kernel<<<NBUK + GB, 256, 0, stream>>>(gcnt, bdata, dinv, rowptr, csr_src,
                                                          x, Wb1t, deg, hsbuf);

    // ---- fused agg1+gemm2: gather hsbuf (fp8,128) -> hs2 fp8[100K x 64] into aggbuf ----
    agg_gemm_kernel<128, 64, true><<<(NN + 31) / 32, 256, 0, stream>>>(
        rowptr, csr_src, hsbuf, dinv, b1, Wb2t, (void*)aggbuf, NN);

    // ---- fused agg2+gemm3: gather aggbuf (fp8,64) -> hs3 bf16[100K x 32] into hsbuf ----
    agg_gemm_kernel<64, 32, false><<<(NN + 63) / 64, 256, 0, stream>>>(
        rowptr, csr_src, (const unsigned char*)aggbuf, dinv, b2, Wb3t, (void*)hsbuf, NN);

    // ---- layer 3 agg (bf16 in, fp32 out); pool ----
    agg3_kernel<<<(NN + 63) / 64, 256, 0, stream>>>(rowptr, csr_src,
        (const unsigned short*)hsbuf, dinv, b3, (float*)aggbuf, NN);
    pool2_kernel<<<NG, 256, 0, stream>>>((const float*)aggbuf, gstart, pooled);

    // ---- epilogue ----
    final_kernel<<<1, 256, 0, stream>>>(pooled, Wl, bl, targets, out);
}

// Round 7
// 299.045 us; speedup vs baseline: 1.1806x; 1.1806x over previous
//
#include <hip/hip_runtime.h>
#include <math.h>

#define NN 100000
#define NE 1600000
#define NG 2048
#define NBUK 391     // ceil(NN/256) dst-buckets, bucket = dst >> 8
#define SLOT 6144    // per-bucket capacity: mean 4096 + 32 sigma
#define CHUNK 8192   // edges per bin block
#define BINB 196     // bin blocks (NE/CHUNK)
#define GEMMB 832    // gemm blocks (3328 waves, ~1.9 m-tiles/wave)

typedef __attribute__((ext_vector_type(8))) short short8;
typedef __attribute__((ext_vector_type(8))) __bf16 bf16x8;
typedef __attribute__((ext_vector_type(4))) float f32x4;
typedef __attribute__((ext_vector_type(2))) float f32x2;
typedef __attribute__((ext_vector_type(4))) unsigned int uint4_;

__device__ __forceinline__ unsigned short f2bf(float f) {       // RNE, finite inputs
    unsigned int u = __float_as_uint(f);
    return (unsigned short)((u + 0x7FFFu + ((u >> 16) & 1u)) >> 16);
}
__device__ __forceinline__ float bf2f(unsigned short s) {
    return __uint_as_float(((unsigned int)s) << 16);
}
__device__ __forceinline__ unsigned char f2fp8(float v) {       // HW cvt, e4m3fn
    int p = __builtin_amdgcn_cvt_pk_fp8_f32(v, v, 0, false);
    return (unsigned char)(p & 0xFF);
}

// ---------------- setup: w2bf (transposed) + grange + gcnt zero + pooled zero ----------------
__global__ __launch_bounds__(256) void setup_kernel(const float* __restrict__ W1,
                                                    const float* __restrict__ W2,
                                                    const float* __restrict__ W3,
                                                    unsigned short* __restrict__ Wb1t,
                                                    unsigned short* __restrict__ Wb2t,
                                                    unsigned short* __restrict__ Wb3t,
                                                    const int* __restrict__ batch,
                                                    int* __restrict__ gstart,
                                                    int* __restrict__ gcnt,
                                                    float* __restrict__ pooled) {
    const int bid = blockIdx.x, t = threadIdx.x;
    if (bid < 104) {                                  // weight cvt+transpose (26624 elems)
        int i = bid * 256 + t;
        if (i < 16384) {                              // W1: 128x128
            int k = i >> 7, c = i & 127;
            Wb1t[c * 128 + k] = f2bf(W1[i]);
        } else if (i < 24576) {                       // W2: 128x64
            int j = i - 16384; int k = j >> 6, c = j & 63;
            Wb2t[c * 128 + k] = f2bf(W2[j]);
        } else if (i < 26624) {                       // W3: 64x32
            int j = i - 24576; int k = j >> 5, c = j & 31;
            Wb3t[c * 64 + k] = f2bf(W3[j]);
        }
    } else if (bid < 113) {                           // grange (batch sorted)
        int g = (bid - 104) * 256 + t;
        if (g > NG) return;
        if (g == NG) { gstart[g] = NN; return; }
        int lo = 0, hi = NN;
        while (lo < hi) { int mid = (lo + hi) >> 1; if (batch[mid] < g) lo = mid + 1; else hi = mid; }
        gstart[g] = lo;
    } else if (bid == 113) {                          // zero gcnt (512 ints)
        gcnt[t] = 0; gcnt[t + 256] = 0;
    } else {                                          // zero pooled sums (NG*32 f32, 256 blocks)
        int i = (bid - 114) * 256 + t;
        if (i < NG * 32) pooled[i] = 0.f;
    }
}

// ---------------- MFMA GEMM body ----------------
// Layouts [m89-verified]: A: m=lane&15, k=quad*8+j ; B: n=lane&15, k=quad*8+j ;
//                         C/D: col=lane&15, row=quad*4+reg.
// SCALE_OUT=false (R19): write raw acc (no dinv) -> gemm1 has NO CSR dependency
// and can co-run with the bin pass; agg1 applies dinv[src] at gather time.
template<int FIN, int FOUT, bool RELU_IN, bool A_BF16, bool OUT_FP8, bool SCALE_OUT>
__device__ __forceinline__ void gemm_body(const void* __restrict__ in_,
                                          const unsigned short* __restrict__ Wbt,
                                          const float* __restrict__ dinv,
                                          void* __restrict__ out,
                                          int N, int nwaves, int wid, int lane) {
    constexpr int NT = FOUT / 16;
    constexpr int KS = FIN / 32;
    const int m16  = lane & 15;
    const int quad = lane >> 4;
    const int koff = quad * 8;

    short8 bfrag[NT][KS];
#pragma unroll
    for (int nt = 0; nt < NT; ++nt) {
        const unsigned short* wcol = Wbt + (size_t)(m16 + nt * 16) * FIN + koff;
#pragma unroll
        for (int ks = 0; ks < KS; ++ks)
            bfrag[nt][ks] = *(const short8*)(wcol + ks * 32);
    }

    const int MT = N / 16;                 // N == 100000 -> exact
    int mt = wid;
    if (mt >= MT) return;

    short8 curB[KS], nxtB[KS];
    f32x4  curF[KS][2], nxtF[KS][2];

    auto load_raw = [&](int m, short8* rb, f32x4 (*rf)[2]) {
        const int row = m * 16 + m16;
        if (A_BF16) {
            const unsigned short* A = (const unsigned short*)in_ + (size_t)row * FIN + koff;
#pragma unroll
            for (int ks = 0; ks < KS; ++ks) rb[ks] = *(const short8*)(A + ks * 32);
        } else {
            const float* A = (const float*)in_ + (size_t)row * FIN + koff;
#pragma unroll
            for (int ks = 0; ks < KS; ++ks) {
                rf[ks][0] = *(const f32x4*)(A + ks * 32);
                rf[ks][1] = *(const f32x4*)(A + ks * 32 + 4);
            }
        }
    };

    load_raw(mt, curB, curF);
    while (true) {
        const int mtn = mt + nwaves;
        const bool have_next = (mtn < MT);
        if (have_next) load_raw(mtn, nxtB, nxtF);   // in flight across the MFMAs below

        short8 afrag[KS];
        if (A_BF16) {
#pragma unroll
            for (int ks = 0; ks < KS; ++ks) {
                short8 a = curB[ks];
                if (RELU_IN) {
#pragma unroll
                    for (int j = 0; j < 8; ++j)
                        a[j] = (short)(((unsigned short)a[j] & 0x8000u) ? 0 : (unsigned short)a[j]);
                }
                afrag[ks] = a;
            }
        } else {
#pragma unroll
            for (int ks = 0; ks < KS; ++ks) {
#pragma unroll
                for (int j = 0; j < 4; ++j) {
                    float a0 = curF[ks][0][j], a1 = curF[ks][1][j];
                    if (RELU_IN) { a0 = fmaxf(a0, 0.f); a1 = fmaxf(a1, 0.f); }
                    afrag[ks][j]     = (short)f2bf(a0);
                    afrag[ks][j + 4] = (short)f2bf(a1);
                }
            }
        }

        f32x4 acc[NT];
#pragma unroll
        for (int nt = 0; nt < NT; ++nt) acc[nt] = (f32x4){0.f, 0.f, 0.f, 0.f};
#pragma unroll
        for (int nt = 0; nt < NT; ++nt)
#pragma unroll
            for (int ks = 0; ks < KS; ++ks)
                acc[nt] = __builtin_amdgcn_mfma_f32_16x16x32_bf16(
                    __builtin_bit_cast(bf16x8, afrag[ks]),
                    __builtin_bit_cast(bf16x8, bfrag[nt][ks]), acc[nt], 0, 0, 0);

        float dv[4];
        if (SCALE_OUT) {
#pragma unroll
            for (int r = 0; r < 4; ++r) dv[r] = dinv[mt * 16 + quad * 4 + r];
        }
#pragma unroll
        for (int nt = 0; nt < NT; ++nt) {
            const int col = m16 + nt * 16;
#pragma unroll
            for (int r = 0; r < 4; ++r) {
                int orow = mt * 16 + quad * 4 + r;
                float v = SCALE_OUT ? acc[nt][r] * dv[r] : acc[nt][r];
                if (OUT_FP8)
                    ((unsigned char*)out)[(size_t)orow * FOUT + col] = f2fp8(v);
                else
                    ((unsigned short*)out)[(size_t)orow * FOUT + col] = f2bf(v);
            }
        }

        if (!have_next) break;
#pragma unroll
        for (int ks = 0; ks < KS; ++ks) {
            curB[ks] = nxtB[ks];
            curF[ks][0] = nxtF[ks][0];
            curF[ks][1] = nxtF[ks][1];
        }
        mt = mtn;
    }
}

// ---------------- fused: edge binning (blocks 0..195) || gemm1-unscaled (rest) ----------------
__global__ __launch_bounds__(256, 2) void bin_gemm1_kernel(const int* __restrict__ src,
                                                           const int* __restrict__ dst,
                                                           int* __restrict__ gcnt,
                                                           int* __restrict__ bucket_data,
                                                           const float* __restrict__ x,
                                                           const unsigned short* __restrict__ Wb1t,
                                                           unsigned char* __restrict__ hs) {
    __shared__ int cnt[512];                 // padded scan array
    __shared__ int offs[NBUK];
    __shared__ int cnt2[NBUK];
    __shared__ int gb[NBUK];
    __shared__ int packB[CHUNK];
    __shared__ unsigned short bktB[CHUNK];
    const int t = threadIdx.x;
    if (blockIdx.x < BINB) {
        const int E0 = blockIdx.x * CHUNK;
        const int valid = min(CHUNK, NE - E0);
        cnt[t] = 0; cnt[t + 256] = 0;
        for (int i = t; i < NBUK; i += 256) cnt2[i] = 0;
        __syncthreads();
        // A: count buckets
        for (int i = t; i < valid; i += 256)
            atomicAdd(&cnt[dst[E0 + i] >> 8], 1);
        __syncthreads();
        int o0 = cnt[t], o1 = cnt[t + 256];
        // B: inclusive Hillis-Steele scan over 512 (2 elems/thread)
        for (int off = 1; off < 512; off <<= 1) {
            int a0 = (t >= off) ? cnt[t - off] : 0;
            int a1 = (t + 256 >= off) ? cnt[t + 256 - off] : 0;
            __syncthreads();
            cnt[t] += a0; cnt[t + 256] += a1;
            __syncthreads();
        }
        if (t < NBUK)       { offs[t] = cnt[t] - o0;             gb[t] = o0 ? atomicAdd(&gcnt[t], o0) : 0; }
        if (t + 256 < NBUK) { offs[t + 256] = cnt[t + 256] - o1; gb[t + 256] = o1 ? atomicAdd(&gcnt[t + 256], o1) : 0; }
        __syncthreads();
        // C: re-read edges, place bucket-sorted into LDS
        for (int i = t; i < valid; i += 256) {
            int s = src[E0 + i], d = dst[E0 + i];
            int b = d >> 8;
            int pos = offs[b] + atomicAdd(&cnt2[b], 1);
            packB[pos] = (s << 8) | (d & 255);
            bktB[pos] = (unsigned short)b;
        }
        __syncthreads();
        // D: contiguous-per-bucket append to global streams
        for (int i = t; i < valid; i += 256) {
            int b = bktB[i];
            int idx = gb[b] + (i - offs[b]);
            if (idx < SLOT) bucket_data[b * SLOT + idx] = packB[i];
        }
    } else {
        const int wid = ((blockIdx.x - BINB) * 256 + t) >> 6;
        gemm_body<128, 128, false, false, true, false>(x, Wb1t, nullptr, hs,
                                                       NN, GEMMB * 4, wid, t & 63);
    }
}

// ---------------- csr2a+fill merged: counts -> dinv/rowptr, then fine-scatter csr_src ----------------
// One bdata pass fewer than the old csr2a-then-fill pair.
__global__ __launch_bounds__(256) void csr2afill_kernel(const int* __restrict__ gcnt,
                                                        const int* __restrict__ bucket_data,
                                                        float* __restrict__ dinv,
                                                        int* __restrict__ rowptr,
                                                        int* __restrict__ csr_src) {
    __shared__ int bs[512];
    __shared__ int counts[256];
    __shared__ int offs[256];
    __shared__ int cnt2[256];
    __shared__ int base_sh;
    const int t = threadIdx.x;
    const int b = blockIdx.x;
    // inline exclusive scan of min(gcnt,SLOT) over all buckets (redundant per block)
    bs[t] = (t < NBUK) ? min(gcnt[t], SLOT) : 0;
    bs[t + 256] = (t + 256 < NBUK) ? min(gcnt[t + 256], SLOT) : 0;
    counts[t] = 0;
    __syncthreads();
    for (int off = 1; off < 512; off <<= 1) {
        int a0 = (t >= off) ? bs[t - off] : 0;
        int a1 = (t + 256 >= off) ? bs[t + 256 - off] : 0;
        __syncthreads();
        bs[t] += a0; bs[t + 256] += a1;
        __syncthreads();
    }
    if (t == 0) base_sh = bs[b] - min(gcnt[b], SLOT);   // exclusive base
    __syncthreads();
    const int cb = min(gcnt[b], SLOT);
    const int* bd = bucket_data + b * SLOT;
    for (int i = t; i < cb; i += 256) atomicAdd(&counts[bd[i] & 255], 1);
    __syncthreads();
    int c = counts[t];
    for (int off = 1; off < 256; off <<= 1) {
        int a = (t >= off) ? counts[t - off] : 0;
        __syncthreads();
        counts[t] += a;
        __syncthreads();
    }
    int rp = base_sh + counts[t] - c;       // rowptr for node b*256+t
    int node = b * 256 + t;
    if (node < NN) {
        dinv[node] = rsqrtf((float)c + 1.0f);
        rowptr[node] = rp;
    }
    offs[t] = rp;
    cnt2[t] = 0;
    __syncthreads();
    // fine-scatter csr_src using in-LDS rowptr
    for (int i = t; i < cb; i += 256) {
        int p = bd[i];
        int local = p & 255;
        int pos = atomicAdd(&cnt2[local], 1);
        csr_src[offs[local] + pos] = p >> 8;   // p>=0, arith shift ok
    }
    if (b == NBUK - 1 && t == 0) rowptr[NN] = NE;
}

// ---------------- fused agg(FIN fp8 gather) + gemm(FIN->FOUT) ----------------
// SCALED=true : table already has dinv folded (layer 2) — R16 path, bit-identical.
// SCALED=false: table is raw h (layer 1); multiply each gathered row by dinv[src]
//   (broadcast 4B L2-resident load per edge) and the self row by dinv[n].
// LDS XOR swizzle (byte ^= (row&7)<<4) fixes the 16-way ds_read_b128 conflict.
// Gather pinned at ~6.25 B/cyc/CU (MSHR x L3-latency) — R13/R15/R16/R17 probes.
template<int FIN, int FOUT, bool OUT_FP8, bool SCALED>
__global__ __launch_bounds__(256) void agg_gemm_kernel(const int* __restrict__ rowptr,
                                                       const int* __restrict__ csr_src,
                                                       const unsigned char* __restrict__ hs,
                                                       const float* __restrict__ dinv,
                                                       const float* __restrict__ bias,
                                                       const unsigned short* __restrict__ Wbt,
                                                       void* __restrict__ out, int N) {
    constexpr int TPN  = FIN / 16;          // lanes per node (16 fp8 = 16 B each)
    constexpr int NPB  = 256 / TPN;         // nodes per block (32 or 64)
    constexpr int NTILE = NPB / 16;         // 16-row m-tiles per block (2 or 4)
    constexpr int WPT  = 4 / NTILE;         // waves per tile (2 or 1)
    constexpr int NT   = FOUT / (16 * WPT); // col-tiles per wave (2 in both cases)
    constexpr int KS   = FIN / 32;
    __shared__ unsigned short lag[NPB * FIN];   // XOR-swizzled rows

    const int t = threadIdx.x;
    const int nb = blockIdx.x;
    const int n = nb * NPB + t / TPN;

    // ---- phase 1: gather-aggregate ----
    if (n < N) {
        const uint4_* hp = (const uint4_*)hs;
        const int lanep = t % TPN;
        const int lrow  = t / TPN;
        const int rstride = FIN / 16;
        const int c16 = lanep * 16;
        const float dvn = dinv[n];
        int row = rowptr[n], end = rowptr[n + 1];
        float acc[16];
        {
            uint4_ u = hp[(size_t)n * rstride + lanep];   // self term
#pragma unroll
            for (int w = 0; w < 4; ++w) {
                f32x2 lo = __builtin_amdgcn_cvt_pk_f32_fp8(u[w], false);
                f32x2 hi = __builtin_amdgcn_cvt_pk_f32_fp8(u[w], true);
                if (SCALED) {
                    acc[w * 4 + 0] = lo[0]; acc[w * 4 + 1] = lo[1];
                    acc[w * 4 + 2] = hi[0]; acc[w * 4 + 3] = hi[1];
                } else {
                    acc[w * 4 + 0] = lo[0] * dvn; acc[w * 4 + 1] = lo[1] * dvn;
                    acc[w * 4 + 2] = hi[0] * dvn; acc[w * 4 + 3] = hi[1] * dvn;
                }
            }
        }
        int j = row;
        for (; j + 4 <= end; j += 4) {
            int s0 = csr_src[j], s1 = csr_src[j + 1], s2 = csr_src[j + 2], s3 = csr_src[j + 3];
            uint4_ u0 = hp[(size_t)s0 * rstride + lanep];
            uint4_ u1 = hp[(size_t)s1 * rstride + lanep];
            uint4_ u2 = hp[(size_t)s2 * rstride + lanep];
            uint4_ u3 = hp[(size_t)s3 * rstride + lanep];
            float w0 = 1.f, w1 = 1.f, w2 = 1.f, w3 = 1.f;
            if (!SCALED) { w0 = dinv[s0]; w1 = dinv[s1]; w2 = dinv[s2]; w3 = dinv[s3]; }
#pragma unroll
            for (int w = 0; w < 4; ++w) {
                f32x2 a0 = __builtin_amdgcn_cvt_pk_f32_fp8(u0[w], false);
                f32x2 b0 = __builtin_amdgcn_cvt_pk_f32_fp8(u0[w], true);
                f32x2 a1 = __builtin_amdgcn_cvt_pk_f32_fp8(u1[w], false);
                f32x2 b1 = __builtin_amdgcn_cvt_pk_f32_fp8(u1[w], true);
                f32x2 a2 = __builtin_amdgcn_cvt_pk_f32_fp8(u2[w], false);
                f32x2 b2 = __builtin_amdgcn_cvt_pk_f32_fp8(u2[w], true);
                f32x2 a3 = __builtin_amdgcn_cvt_pk_f32_fp8(u3[w], false);
                f32x2 b3 = __builtin_amdgcn_cvt_pk_f32_fp8(u3[w], true);
                if (SCALED) {
                    acc[w * 4 + 0] += (a0[0] + a1[0]) + (a2[0] + a3[0]);
                    acc[w * 4 + 1] += (a0[1] + a1[1]) + (a2[1] + a3[1]);
                    acc[w * 4 + 2] += (b0[0] + b1[0]) + (b2[0] + b3[0]);
                    acc[w * 4 + 3] += (b0[1] + b1[1]) + (b2[1] + b3[1]);
                } else {
                    acc[w * 4 + 0] += fmaf(a0[0], w0, a1[0] * w1) + fmaf(a2[0], w2, a3[0] * w3);
                    acc[w * 4 + 1] += fmaf(a0[1], w0, a1[1] * w1) + fmaf(a2[1], w2, a3[1] * w3);
                    acc[w * 4 + 2] += fmaf(b0[0], w0, b1[0] * w1) + fmaf(b2[0], w2, b3[0] * w3);
                    acc[w * 4 + 3] += fmaf(b0[1], w0, b1[1] * w1) + fmaf(b2[1], w2, b3[1] * w3);
                }
            }
        }
        for (; j < end; ++j) {
            int s = csr_src[j];
            uint4_ u = hp[(size_t)s * rstride + lanep];
            float wv = SCALED ? 1.f : dinv[s];
#pragma unroll
            for (int w = 0; w < 4; ++w) {
                f32x2 lo = __builtin_amdgcn_cvt_pk_f32_fp8(u[w], false);
                f32x2 hi = __builtin_amdgcn_cvt_pk_f32_fp8(u[w], true);
                if (SCALED) {
                    acc[w * 4 + 0] += lo[0]; acc[w * 4 + 1] += lo[1];
                    acc[w * 4 + 2] += hi[0]; acc[w * 4 + 3] += hi[1];
                } else {
                    acc[w * 4 + 0] = fmaf(lo[0], wv, acc[w * 4 + 0]);
                    acc[w * 4 + 1] = fmaf(lo[1], wv, acc[w * 4 + 1]);
                    acc[w * 4 + 2] = fmaf(hi[0], wv, acc[w * 4 + 2]);
                    acc[w * 4 + 3] = fmaf(hi[1], wv, acc[w * 4 + 3]);
                }
            }
        }
        short8 o0, o1;
#pragma unroll
        for (int k = 0; k < 8; ++k) {
            unsigned short s0 = f2bf(fmaf(acc[k],     dvn, bias[c16 + k]));
            unsigned short s1 = f2bf(fmaf(acc[k + 8], dvn, bias[c16 + 8 + k]));
            o0[k] = (short)((s0 & 0x8000u) ? 0 : s0);   // relu folded
            o1[k] = (short)((s1 & 0x8000u) ? 0 : s1);
        }
        const unsigned int bofs = (unsigned)(lrow * (FIN * 2) + c16 * 2);
        const unsigned int msk  = (unsigned)((lrow & 7) << 4);
        *(short8*)((char*)lag + (bofs ^ msk)) = o0;
        *(short8*)((char*)lag + ((bofs + 16) ^ msk)) = o1;
    }
    __syncthreads();

    // ---- phase 2: GEMM m-tiles of this block's rows from LDS (swizzled reads) ----
    const int lane = t & 63, wv = t >> 6;
    const int m16 = lane & 15, quad = lane >> 4;
    const int tile = wv / WPT, ch = wv - tile * WPT;
    const int colb = ch * NT * 16;

    short8 bfrag[NT][KS];
#pragma unroll
    for (int nt = 0; nt < NT; ++nt) {
        const unsigned short* wcol = Wbt + (size_t)(colb + nt * 16 + m16) * FIN + quad * 8;
#pragma unroll
        for (int ks = 0; ks < KS; ++ks)
            bfrag[nt][ks] = *(const short8*)(wcol + ks * 32);
    }
    short8 afrag[KS];
    const int arow = tile * 16 + m16;
    const unsigned int abase = (unsigned)(arow * (FIN * 2) + quad * 16);
    const unsigned int am    = (unsigned)((arow & 7) << 4);
#pragma unroll
    for (int ks = 0; ks < KS; ++ks)
        afrag[ks] = *(const short8*)((char*)lag + ((abase + (unsigned)(ks * 64)) ^ am));

    f32x4 acc2[NT];
#pragma unroll
    for (int nt = 0; nt < NT; ++nt) acc2[nt] = (f32x4){0.f, 0.f, 0.f, 0.f};
#pragma unroll
    for (int nt = 0; nt < NT; ++nt)
#pragma unroll
        for (int ks = 0; ks < KS; ++ks)
            acc2[nt] = __builtin_amdgcn_mfma_f32_16x16x32_bf16(
                __builtin_bit_cast(bf16x8, afrag[ks]),
                __builtin_bit_cast(bf16x8, bfrag[nt][ks]), acc2[nt], 0, 0, 0);

    const int rbase = nb * NPB + tile * 16 + quad * 4;
    float dv[4];
#pragma unroll
    for (int r = 0; r < 4; ++r) dv[r] = dinv[min(rbase + r, N - 1)];
#pragma unroll
    for (int nt = 0; nt < NT; ++nt) {
        const int col = colb + nt * 16 + m16;
#pragma unroll
        for (int r = 0; r < 4; ++r) {
            int orow = rbase + r;
            if (orow < N) {
                float v = acc2[nt][r] * dv[r];
                if (OUT_FP8)
                    ((unsigned char*)out)[(size_t)orow * FOUT + col] = f2fp8(v);
                else
                    ((unsigned short*)out)[(size_t)orow * FOUT + col] = f2bf(v);
            }
        }
    }
}

// ---------------- layer-3 agg (bf16 gather) + pool fused: per-block graph partials ----------------
// Nodes are graph-contiguous (batch sorted), so a 64-node block spans <=64 graphs.
// Accumulate agg3 rows into LDS partials, flush once per (graph,col) via atomics.
// Saves the 12.8MB aggout write + pool2's read + 2 launches. pooled holds SUMS;
// final_kernel divides by count. f32 atomic order nondeterminism ~1e-6 — ok.
__global__ __launch_bounds__(256) void agg3pool_kernel(const int* __restrict__ rowptr,
                                                       const int* __restrict__ csr_src,
                                                       const unsigned short* __restrict__ hs,
                                                       const float* __restrict__ dinv,
                                                       const float* __restrict__ b,
                                                       const int* __restrict__ batch,
                                                       float* __restrict__ pooled, int N) {
    constexpr int F = 32, TPN = 4, NPB = 64;
    __shared__ float part[NPB + 2][32];
    __shared__ int gmin_sh, gmax_sh;
    const int base = blockIdx.x * NPB;
    const int n = base + threadIdx.x / TPN;
    const int c8 = (threadIdx.x % TPN) * 8;
    if (threadIdx.x == 0) gmin_sh = batch[min(base, N - 1)];
    if (threadIdx.x == 1) gmax_sh = batch[min(base + NPB - 1, N - 1)];
    for (int i = threadIdx.x; i < (NPB + 2) * 32; i += 256) ((float*)part)[i] = 0.f;
    __syncthreads();
    const int gmin = gmin_sh;
    if (n < N) {
        int row = rowptr[n], end = rowptr[n + 1];
        float acc[8];
        {
            short8 h = *(const short8*)(hs + (size_t)n * F + c8);   // self term
#pragma unroll
            for (int j = 0; j < 8; ++j) acc[j] = bf2f((unsigned short)h[j]);
        }
        int j = row;
        for (; j + 4 <= end; j += 4) {
            int s0 = csr_src[j], s1 = csr_src[j + 1], s2 = csr_src[j + 2], s3 = csr_src[j + 3];
            short8 h0 = *(const short8*)(hs + (size_t)s0 * F + c8);
            short8 h1 = *(const short8*)(hs + (size_t)s1 * F + c8);
            short8 h2 = *(const short8*)(hs + (size_t)s2 * F + c8);
            short8 h3 = *(const short8*)(hs + (size_t)s3 * F + c8);
#pragma unroll
            for (int k = 0; k < 8; ++k)
                acc[k] += (bf2f((unsigned short)h0[k]) + bf2f((unsigned short)h1[k])) +
                          (bf2f((unsigned short)h2[k]) + bf2f((unsigned short)h3[k]));
        }
        for (; j < end; ++j) {
            int s = csr_src[j];
            short8 h = *(const short8*)(hs + (size_t)s * F + c8);
#pragma unroll
            for (int k = 0; k < 8; ++k) acc[k] += bf2f((unsigned short)h[k]);
        }
        float c = dinv[n];
        int slot = batch[n] - gmin;
#pragma unroll
        for (int k = 0; k < 8; ++k)
            atomicAdd(&part[slot][c8 + k], fmaf(acc[k], c, b[c8 + k]));
    }
    __syncthreads();
    const int gspan = gmax_sh - gmin + 1;
    for (int i = threadIdx.x; i < gspan * 32; i += 256) {
        float v = part[i >> 5][i & 31];
        if (v != 0.f) atomicAdd(&pooled[(size_t)(gmin + (i >> 5)) * 32 + (i & 31)], v);
    }
}

// ---------------- epilogue: mean, logits, sigmoid, BCE ----------------
__global__ __launch_bounds__(256) void final_kernel(const float* __restrict__ pooled,
                                                    const int* __restrict__ gstart,
                                                    const float* __restrict__ Wl,
                                                    const float* __restrict__ bl,
                                                    const int* __restrict__ targets,
                                                    float* __restrict__ out) {
    __shared__ float red[256];
    float lsum = 0.0f;
    for (int g = threadIdx.x; g < NG; g += 256) {
        float cntf = fmaxf((float)(gstart[g + 1] - gstart[g]), 1.0f);
        float acc = bl[0];
#pragma unroll
        for (int k = 0; k < 32; ++k)
            acc = fmaf(pooled[(size_t)g * 32 + k] / cntf, Wl[k], acc);
        out[g] = 1.0f / (1.0f + expf(-acc));
        float y = (float)targets[g];
        lsum += fmaxf(acc, 0.0f) - acc * y + log1pf(expf(-fabsf(acc)));
    }
    red[threadIdx.x] = lsum;
    __syncthreads();
    for (int s = 128; s > 0; s >>= 1) {
        if (threadIdx.x < s) red[threadIdx.x] += red[threadIdx.x + s];
        __syncthreads();
    }
    if (threadIdx.x == 0) out[NG] = red[0] / (float)NG;
}

extern "C" void kernel_launch(void* const* d_in, const int* in_sizes, int n_in,
                              void* d_out, int out_size, void* d_ws, size_t ws_size,
                              hipStream_t stream) {
    const float* x       = (const float*)d_in[0];
    const int*   ei      = (const int*)d_in[1];
    const int*   batch   = (const int*)d_in[2];
    const int*   targets = (const int*)d_in[3];
    const float* W1 = (const float*)d_in[4];
    const float* b1 = (const float*)d_in[5];
    const float* W2 = (const float*)d_in[6];
    const float* b2 = (const float*)d_in[7];
    const float* W3 = (const float*)d_in[8];
    const float* b3 = (const float*)d_in[9];
    const float* Wl = (const float*)d_in[10];
    const float* bl = (const float*)d_in[11];
    float* out = (float*)d_out;
    char*  ws  = (char*)d_ws;

    const int* src = ei;
    const int* dst = ei + NE;

    // workspace layout (byte offsets, 512B aligned) — total ~68.3 MB
    float*          dinv    = (float*)(ws);                    //    400,384 B
    int*            rowptr  = (int*)(ws + 400384);             //    400,384 B (NN+1)
    int*            csr_src = (int*)(ws + 800768);             //  6,400,512 B
    unsigned short* Wb1t    = (unsigned short*)(ws + 7201280); //     32,768 B (transposed)
    unsigned short* Wb2t    = (unsigned short*)(ws + 7234048); //     16,384 B (transposed)
    unsigned short* Wb3t    = (unsigned short*)(ws + 7250432); //      4,096 B (transposed)
    int*            gstart  = (int*)(ws + 7254528);            //      8,704 B (NG+1)
    unsigned char*  hsbuf   = (unsigned char*)(ws + 7263232);  // 12.8 MB fp8 hu / 6.4 MB bf16 hs3
    unsigned short* aggbuf  = (unsigned short*)(ws + 32863744);// fp8 hs2 [100K x 64]
    float*          pooled  = (float*)(ws + 58464256);         //    262,144 B (sums)
    int*            bdata   = (int*)(ws + 58726400);           //  9,609,216 B (391*6144*4)
    int*            gcnt    = (int*)(ws + 68335616);           //      2,048 B

    // ---- setup (w2bf + grange + gcnt zero + pooled zero) ----
    setup_kernel<<<370, 256, 0, stream>>>(W1, W2, W3, Wb1t, Wb2t, Wb3t, batch, gstart, gcnt, pooled);

    // ---- bin || gemm1-unscaled (no CSR dependency: hu = fp8(x@W1)) ----
    bin_gemm1_kernel<<<BINB + GEMMB, 256, 0, stream>>>(src, dst, gcnt, bdata, x, Wb1t, hsbuf);

    // ---- csr2a+fill merged: dinv, rowptr, csr_src in one bdata pass ----
    csr2afill_kernel<<<NBUK, 256, 0, stream>>>(gcnt, bdata, dinv, rowptr, csr_src);

    // ---- fused agg1+gemm2 (UNSCALED table: gathers dinv[src]) -> hs2 fp8[100K x 64] ----
    agg_gemm_kernel<128, 64, true, false><<<(NN + 31) / 32, 256, 0, stream>>>(
        rowptr, csr_src, hsbuf, dinv, b1, Wb2t, (void*)aggbuf, NN);

    // ---- fused agg2+gemm3 (SCALED table) -> hs3 bf16[100K x 32] ----
    agg_gemm_kernel<64, 32, false, true><<<(NN + 63) / 64, 256, 0, stream>>>(
        rowptr, csr_src, (const unsigned char*)aggbuf, dinv, b2, Wb3t, (void*)hsbuf, NN);

    // ---- layer 3 agg + pool fused (graph partials -> pooled sums) ----
    agg3pool_kernel<<<(NN + 63) / 64, 256, 0, stream>>>(rowptr, csr_src,
        (const unsigned short*)hsbuf, dinv, b3, batch, pooled, NN);

    // ---- epilogue (mean + logits + BCE) ----
    final_kernel<<<1, 256, 0, stream>>>(pooled, gstart, Wl, bl, targets, out);
}

// Round 8
// 294.958 us; speedup vs baseline: 1.1969x; 1.0139x over previous
//
#include <hip/hip_runtime.h>
#include <math.h>

#define NN 100000
#define NE 1600000
#define NG 2048
#define NBUK 391     // ceil(NN/256) dst-buckets, bucket = dst >> 8
#define SLOT 6144    // per-bucket capacity: mean 4096 + 32 sigma
#define CHUNK 4096   // edges per bin block (R20: halved -> ~31KB LDS, 4 blocks/CU fused)
#define BINB 391     // bin blocks (ceil(NE/CHUNK))
#define MT_ALL 6250  // m-tiles for gemm1 (NN/16)
#define MT_SPLIT 3750// gemm1a covers [0,MT_SPLIT) with bin; gemm1b rest with csr2afill
#define GA 600       // gemm1a blocks (2400 waves)
#define GB 440       // gemm1b blocks (1760 waves)

typedef __attribute__((ext_vector_type(8))) short short8;
typedef __attribute__((ext_vector_type(8))) __bf16 bf16x8;
typedef __attribute__((ext_vector_type(4))) float f32x4;
typedef __attribute__((ext_vector_type(2))) float f32x2;
typedef __attribute__((ext_vector_type(4))) unsigned int uint4_;

__device__ __forceinline__ unsigned short f2bf(float f) {       // RNE, finite inputs
    unsigned int u = __float_as_uint(f);
    return (unsigned short)((u + 0x7FFFu + ((u >> 16) & 1u)) >> 16);
}
__device__ __forceinline__ float bf2f(unsigned short s) {
    return __uint_as_float(((unsigned int)s) << 16);
}
__device__ __forceinline__ unsigned char f2fp8(float v) {       // HW cvt, e4m3fn
    int p = __builtin_amdgcn_cvt_pk_fp8_f32(v, v, 0, false);
    return (unsigned char)(p & 0xFF);
}

// ---------------- setup: w2bf (transposed) + grange + gcnt zero + pooled zero ----------------
__global__ __launch_bounds__(256) void setup_kernel(const float* __restrict__ W1,
                                                    const float* __restrict__ W2,
                                                    const float* __restrict__ W3,
                                                    unsigned short* __restrict__ Wb1t,
                                                    unsigned short* __restrict__ Wb2t,
                                                    unsigned short* __restrict__ Wb3t,
                                                    const int* __restrict__ batch,
                                                    int* __restrict__ gstart,
                                                    int* __restrict__ gcnt,
                                                    float* __restrict__ pooled) {
    const int bid = blockIdx.x, t = threadIdx.x;
    if (bid < 104) {                                  // weight cvt+transpose (26624 elems)
        int i = bid * 256 + t;
        if (i < 16384) {                              // W1: 128x128
            int k = i >> 7, c = i & 127;
            Wb1t[c * 128 + k] = f2bf(W1[i]);
        } else if (i < 24576) {                       // W2: 128x64
            int j = i - 16384; int k = j >> 6, c = j & 63;
            Wb2t[c * 128 + k] = f2bf(W2[j]);
        } else if (i < 26624) {                       // W3: 64x32
            int j = i - 24576; int k = j >> 5, c = j & 31;
            Wb3t[c * 64 + k] = f2bf(W3[j]);
        }
    } else if (bid < 113) {                           // grange (batch sorted)
        int g = (bid - 104) * 256 + t;
        if (g > NG) return;
        if (g == NG) { gstart[g] = NN; return; }
        int lo = 0, hi = NN;
        while (lo < hi) { int mid = (lo + hi) >> 1; if (batch[mid] < g) lo = mid + 1; else hi = mid; }
        gstart[g] = lo;
    } else if (bid == 113) {                          // zero gcnt (512 ints)
        gcnt[t] = 0; gcnt[t + 256] = 0;
    } else {                                          // zero pooled sums (NG*32 f32, 256 blocks)
        int i = (bid - 114) * 256 + t;
        if (i < NG * 32) pooled[i] = 0.f;
    }
}

// ---------------- MFMA GEMM body ----------------
// Layouts [m89-verified]: A: m=lane&15, k=quad*8+j ; B: n=lane&15, k=quad*8+j ;
//                         C/D: col=lane&15, row=quad*4+reg.
// SCALE_OUT=false: write raw acc (no dinv) -> gemm1 has NO CSR dependency and
// co-runs with bin/csr2afill; agg1 applies dinv[src] at gather (R19-verified).
template<int FIN, int FOUT, bool RELU_IN, bool A_BF16, bool OUT_FP8, bool SCALE_OUT>
__device__ __forceinline__ void gemm_body(const void* __restrict__ in_,
                                          const unsigned short* __restrict__ Wbt,
                                          const float* __restrict__ dinv,
                                          void* __restrict__ out,
                                          int mt0, int mt1, int nwaves, int wid, int lane) {
    constexpr int NT = FOUT / 16;
    constexpr int KS = FIN / 32;
    const int m16  = lane & 15;
    const int quad = lane >> 4;
    const int koff = quad * 8;

    short8 bfrag[NT][KS];
#pragma unroll
    for (int nt = 0; nt < NT; ++nt) {
        const unsigned short* wcol = Wbt + (size_t)(m16 + nt * 16) * FIN + koff;
#pragma unroll
        for (int ks = 0; ks < KS; ++ks)
            bfrag[nt][ks] = *(const short8*)(wcol + ks * 32);
    }

    int mt = mt0 + wid;
    if (mt >= mt1) return;

    short8 curB[KS], nxtB[KS];
    f32x4  curF[KS][2], nxtF[KS][2];

    auto load_raw = [&](int m, short8* rb, f32x4 (*rf)[2]) {
        const int row = m * 16 + m16;
        if (A_BF16) {
            const unsigned short* A = (const unsigned short*)in_ + (size_t)row * FIN + koff;
#pragma unroll
            for (int ks = 0; ks < KS; ++ks) rb[ks] = *(const short8*)(A + ks * 32);
        } else {
            const float* A = (const float*)in_ + (size_t)row * FIN + koff;
#pragma unroll
            for (int ks = 0; ks < KS; ++ks) {
                rf[ks][0] = *(const f32x4*)(A + ks * 32);
                rf[ks][1] = *(const f32x4*)(A + ks * 32 + 4);
            }
        }
    };

    load_raw(mt, curB, curF);
    while (true) {
        const int mtn = mt + nwaves;
        const bool have_next = (mtn < mt1);
        if (have_next) load_raw(mtn, nxtB, nxtF);   // in flight across the MFMAs below

        short8 afrag[KS];
        if (A_BF16) {
#pragma unroll
            for (int ks = 0; ks < KS; ++ks) {
                short8 a = curB[ks];
                if (RELU_IN) {
#pragma unroll
                    for (int j = 0; j < 8; ++j)
                        a[j] = (short)(((unsigned short)a[j] & 0x8000u) ? 0 : (unsigned short)a[j]);
                }
                afrag[ks] = a;
            }
        } else {
#pragma unroll
            for (int ks = 0; ks < KS; ++ks) {
#pragma unroll
                for (int j = 0; j < 4; ++j) {
                    float a0 = curF[ks][0][j], a1 = curF[ks][1][j];
                    if (RELU_IN) { a0 = fmaxf(a0, 0.f); a1 = fmaxf(a1, 0.f); }
                    afrag[ks][j]     = (short)f2bf(a0);
                    afrag[ks][j + 4] = (short)f2bf(a1);
                }
            }
        }

        f32x4 acc[NT];
#pragma unroll
        for (int nt = 0; nt < NT; ++nt) acc[nt] = (f32x4){0.f, 0.f, 0.f, 0.f};
#pragma unroll
        for (int nt = 0; nt < NT; ++nt)
#pragma unroll
            for (int ks = 0; ks < KS; ++ks)
                acc[nt] = __builtin_amdgcn_mfma_f32_16x16x32_bf16(
                    __builtin_bit_cast(bf16x8, afrag[ks]),
                    __builtin_bit_cast(bf16x8, bfrag[nt][ks]), acc[nt], 0, 0, 0);

        float dv[4];
        if (SCALE_OUT) {
#pragma unroll
            for (int r = 0; r < 4; ++r) dv[r] = dinv[mt * 16 + quad * 4 + r];
        }
#pragma unroll
        for (int nt = 0; nt < NT; ++nt) {
            const int col = m16 + nt * 16;
#pragma unroll
            for (int r = 0; r < 4; ++r) {
                int orow = mt * 16 + quad * 4 + r;
                float v = SCALE_OUT ? acc[nt][r] * dv[r] : acc[nt][r];
                if (OUT_FP8)
                    ((unsigned char*)out)[(size_t)orow * FOUT + col] = f2fp8(v);
                else
                    ((unsigned short*)out)[(size_t)orow * FOUT + col] = f2bf(v);
            }
        }

        if (!have_next) break;
#pragma unroll
        for (int ks = 0; ks < KS; ++ks) {
            curB[ks] = nxtB[ks];
            curF[ks][0] = nxtF[ks][0];
            curF[ks][1] = nxtF[ks][1];
        }
        mt = mtn;
    }
}

// ---------------- fused: edge binning (blocks 0..390) || gemm1a-unscaled (rest) ----------------
// CHUNK=4096 keeps the LDS union ~31KB so gemm blocks get 4/CU (R19's 56KB -> 2/CU was the regression).
__global__ __launch_bounds__(256, 2) void bin_gemm1_kernel(const int* __restrict__ src,
                                                           const int* __restrict__ dst,
                                                           int* __restrict__ gcnt,
                                                           int* __restrict__ bucket_data,
                                                           const float* __restrict__ x,
                                                           const unsigned short* __restrict__ Wb1t,
                                                           unsigned char* __restrict__ hs) {
    __shared__ int cnt[512];                 // padded scan array
    __shared__ int offs[NBUK];
    __shared__ int cnt2[NBUK];
    __shared__ int gb[NBUK];
    __shared__ int packB[CHUNK];
    __shared__ unsigned short bktB[CHUNK];
    const int t = threadIdx.x;
    if (blockIdx.x < BINB) {
        const int E0 = blockIdx.x * CHUNK;
        const int valid = min(CHUNK, NE - E0);
        cnt[t] = 0; cnt[t + 256] = 0;
        for (int i = t; i < NBUK; i += 256) cnt2[i] = 0;
        __syncthreads();
        // A: count buckets
        for (int i = t; i < valid; i += 256)
            atomicAdd(&cnt[dst[E0 + i] >> 8], 1);
        __syncthreads();
        int o0 = cnt[t], o1 = cnt[t + 256];
        // B: inclusive Hillis-Steele scan over 512 (2 elems/thread)
        for (int off = 1; off < 512; off <<= 1) {
            int a0 = (t >= off) ? cnt[t - off] : 0;
            int a1 = (t + 256 >= off) ? cnt[t + 256 - off] : 0;
            __syncthreads();
            cnt[t] += a0; cnt[t + 256] += a1;
            __syncthreads();
        }
        if (t < NBUK)       { offs[t] = cnt[t] - o0;             gb[t] = o0 ? atomicAdd(&gcnt[t], o0) : 0; }
        if (t + 256 < NBUK) { offs[t + 256] = cnt[t + 256] - o1; gb[t + 256] = o1 ? atomicAdd(&gcnt[t + 256], o1) : 0; }
        __syncthreads();
        // C: re-read edges, place bucket-sorted into LDS
        for (int i = t; i < valid; i += 256) {
            int s = src[E0 + i], d = dst[E0 + i];
            int b = d >> 8;
            int pos = offs[b] + atomicAdd(&cnt2[b], 1);
            packB[pos] = (s << 8) | (d & 255);
            bktB[pos] = (unsigned short)b;
        }
        __syncthreads();
        // D: contiguous-per-bucket append to global streams
        for (int i = t; i < valid; i += 256) {
            int b = bktB[i];
            int idx = gb[b] + (i - offs[b]);
            if (idx < SLOT) bucket_data[b * SLOT + idx] = packB[i];
        }
    } else {
        const int wid = ((blockIdx.x - BINB) * 256 + t) >> 6;
        gemm_body<128, 128, false, false, true, false>(x, Wb1t, nullptr, hs,
                                                       0, MT_SPLIT, GA * 4, wid, t & 63);
    }
}

// ---------------- fused: csr2a+fill merged (blocks 0..390) || gemm1b-unscaled (rest) ----------------
__global__ __launch_bounds__(256, 2) void csr2afill_gemm1_kernel(const int* __restrict__ gcnt,
                                                                 const int* __restrict__ bucket_data,
                                                                 float* __restrict__ dinv,
                                                                 int* __restrict__ rowptr,
                                                                 int* __restrict__ csr_src,
                                                                 const float* __restrict__ x,
                                                                 const unsigned short* __restrict__ Wb1t,
                                                                 unsigned char* __restrict__ hs) {
    __shared__ int bs[512];
    __shared__ int counts[256];
    __shared__ int offs[256];
    __shared__ int cnt2[256];
    __shared__ int base_sh;
    const int t = threadIdx.x;
    if (blockIdx.x < NBUK) {
        const int b = blockIdx.x;
        // inline exclusive scan of min(gcnt,SLOT) over all buckets (redundant per block)
        bs[t] = (t < NBUK) ? min(gcnt[t], SLOT) : 0;
        bs[t + 256] = (t + 256 < NBUK) ? min(gcnt[t + 256], SLOT) : 0;
        counts[t] = 0;
        __syncthreads();
        for (int off = 1; off < 512; off <<= 1) {
            int a0 = (t >= off) ? bs[t - off] : 0;
            int a1 = (t + 256 >= off) ? bs[t + 256 - off] : 0;
            __syncthreads();
            bs[t] += a0; bs[t + 256] += a1;
            __syncthreads();
        }
        if (t == 0) base_sh = bs[b] - min(gcnt[b], SLOT);   // exclusive base
        __syncthreads();
        const int cb = min(gcnt[b], SLOT);
        const int* bd = bucket_data + b * SLOT;
        for (int i = t; i < cb; i += 256) atomicAdd(&counts[bd[i] & 255], 1);
        __syncthreads();
        int c = counts[t];
        for (int off = 1; off < 256; off <<= 1) {
            int a = (t >= off) ? counts[t - off] : 0;
            __syncthreads();
            counts[t] += a;
            __syncthreads();
        }
        int rp = base_sh + counts[t] - c;       // rowptr for node b*256+t
        int node = b * 256 + t;
        if (node < NN) {
            dinv[node] = rsqrtf((float)c + 1.0f);
            rowptr[node] = rp;
        }
        offs[t] = rp;
        cnt2[t] = 0;
        __syncthreads();
        // fine-scatter csr_src using in-LDS rowptr
        for (int i = t; i < cb; i += 256) {
            int p = bd[i];
            int local = p & 255;
            int pos = atomicAdd(&cnt2[local], 1);
            csr_src[offs[local] + pos] = p >> 8;   // p>=0, arith shift ok
        }
        if (b == NBUK - 1 && t == 0) rowptr[NN] = NE;
    } else {
        const int wid = ((blockIdx.x - NBUK) * 256 + t) >> 6;
        gemm_body<128, 128, false, false, true, false>(x, Wb1t, nullptr, hs,
                                                       MT_SPLIT, MT_ALL, GB * 4, wid, t & 63);
    }
}

// ---------------- fused agg(FIN fp8 gather) + gemm(FIN->FOUT) ----------------
// SCALED=true : table already has dinv folded (layer 2) — bit-identical R16 path.
// SCALED=false: table is raw h (layer 1); multiply gathered rows by dinv[src]
//   (broadcast 4B L2-resident load/edge) and self by dinv[n]. R19-verified.
// LDS XOR swizzle (byte ^= (row&7)<<4) fixes the 16-way ds_read_b128 conflict.
// Gather pinned at ~6.25 B/cyc/CU (MSHR x L3-latency) — R13/R15/R16/R17 probes.
template<int FIN, int FOUT, bool OUT_FP8, bool SCALED>
__global__ __launch_bounds__(256) void agg_gemm_kernel(const int* __restrict__ rowptr,
                                                       const int* __restrict__ csr_src,
                                                       const unsigned char* __restrict__ hs,
                                                       const float* __restrict__ dinv,
                                                       const float* __restrict__ bias,
                                                       const unsigned short* __restrict__ Wbt,
                                                       void* __restrict__ out, int N) {
    constexpr int TPN  = FIN / 16;          // lanes per node (16 fp8 = 16 B each)
    constexpr int NPB  = 256 / TPN;         // nodes per block (32 or 64)
    constexpr int NTILE = NPB / 16;         // 16-row m-tiles per block (2 or 4)
    constexpr int WPT  = 4 / NTILE;         // waves per tile (2 or 1)
    constexpr int NT   = FOUT / (16 * WPT); // col-tiles per wave (2 in both cases)
    constexpr int KS   = FIN / 32;
    __shared__ unsigned short lag[NPB * FIN];   // XOR-swizzled rows

    const int t = threadIdx.x;
    const int nb = blockIdx.x;
    const int n = nb * NPB + t / TPN;

    // ---- phase 1: gather-aggregate ----
    if (n < N) {
        const uint4_* hp = (const uint4_*)hs;
        const int lanep = t % TPN;
        const int lrow  = t / TPN;
        const int rstride = FIN / 16;
        const int c16 = lanep * 16;
        const float dvn = dinv[n];
        int row = rowptr[n], end = rowptr[n + 1];
        float acc[16];
        {
            uint4_ u = hp[(size_t)n * rstride + lanep];   // self term
#pragma unroll
            for (int w = 0; w < 4; ++w) {
                f32x2 lo = __builtin_amdgcn_cvt_pk_f32_fp8(u[w], false);
                f32x2 hi = __builtin_amdgcn_cvt_pk_f32_fp8(u[w], true);
                if (SCALED) {
                    acc[w * 4 + 0] = lo[0]; acc[w * 4 + 1] = lo[1];
                    acc[w * 4 + 2] = hi[0]; acc[w * 4 + 3] = hi[1];
                } else {
                    acc[w * 4 + 0] = lo[0] * dvn; acc[w * 4 + 1] = lo[1] * dvn;
                    acc[w * 4 + 2] = hi[0] * dvn; acc[w * 4 + 3] = hi[1] * dvn;
                }
            }
        }
        int j = row;
        for (; j + 4 <= end; j += 4) {
            int s0 = csr_src[j], s1 = csr_src[j + 1], s2 = csr_src[j + 2], s3 = csr_src[j + 3];
            uint4_ u0 = hp[(size_t)s0 * rstride + lanep];
            uint4_ u1 = hp[(size_t)s1 * rstride + lanep];
            uint4_ u2 = hp[(size_t)s2 * rstride + lanep];
            uint4_ u3 = hp[(size_t)s3 * rstride + lanep];
            float w0 = 1.f, w1 = 1.f, w2 = 1.f, w3 = 1.f;
            if (!SCALED) { w0 = dinv[s0]; w1 = dinv[s1]; w2 = dinv[s2]; w3 = dinv[s3]; }
#pragma unroll
            for (int w = 0; w < 4; ++w) {
                f32x2 a0 = __builtin_amdgcn_cvt_pk_f32_fp8(u0[w], false);
                f32x2 b0 = __builtin_amdgcn_cvt_pk_f32_fp8(u0[w], true);
                f32x2 a1 = __builtin_amdgcn_cvt_pk_f32_fp8(u1[w], false);
                f32x2 b1 = __builtin_amdgcn_cvt_pk_f32_fp8(u1[w], true);
                f32x2 a2 = __builtin_amdgcn_cvt_pk_f32_fp8(u2[w], false);
                f32x2 b2 = __builtin_amdgcn_cvt_pk_f32_fp8(u2[w], true);
                f32x2 a3 = __builtin_amdgcn_cvt_pk_f32_fp8(u3[w], false);
                f32x2 b3 = __builtin_amdgcn_cvt_pk_f32_fp8(u3[w], true);
                if (SCALED) {
                    acc[w * 4 + 0] += (a0[0] + a1[0]) + (a2[0] + a3[0]);
                    acc[w * 4 + 1] += (a0[1] + a1[1]) + (a2[1] + a3[1]);
                    acc[w * 4 + 2] += (b0[0] + b1[0]) + (b2[0] + b3[0]);
                    acc[w * 4 + 3] += (b0[1] + b1[1]) + (b2[1] + b3[1]);
                } else {
                    acc[w * 4 + 0] += fmaf(a0[0], w0, a1[0] * w1) + fmaf(a2[0], w2, a3[0] * w3);
                    acc[w * 4 + 1] += fmaf(a0[1], w0, a1[1] * w1) + fmaf(a2[1], w2, a3[1] * w3);
                    acc[w * 4 + 2] += fmaf(b0[0], w0, b1[0] * w1) + fmaf(b2[0], w2, b3[0] * w3);
                    acc[w * 4 + 3] += fmaf(b0[1], w0, b1[1] * w1) + fmaf(b2[1], w2, b3[1] * w3);
                }
            }
        }
        for (; j < end; ++j) {
            int s = csr_src[j];
            uint4_ u = hp[(size_t)s * rstride + lanep];
            float wv = SCALED ? 1.f : dinv[s];
#pragma unroll
            for (int w = 0; w < 4; ++w) {
                f32x2 lo = __builtin_amdgcn_cvt_pk_f32_fp8(u[w], false);
                f32x2 hi = __builtin_amdgcn_cvt_pk_f32_fp8(u[w], true);
                if (SCALED) {
                    acc[w * 4 + 0] += lo[0]; acc[w * 4 + 1] += lo[1];
                    acc[w * 4 + 2] += hi[0]; acc[w * 4 + 3] += hi[1];
                } else {
                    acc[w * 4 + 0] = fmaf(lo[0], wv, acc[w * 4 + 0]);
                    acc[w * 4 + 1] = fmaf(lo[1], wv, acc[w * 4 + 1]);
                    acc[w * 4 + 2] = fmaf(hi[0], wv, acc[w * 4 + 2]);
                    acc[w * 4 + 3] = fmaf(hi[1], wv, acc[w * 4 + 3]);
                }
            }
        }
        short8 o0, o1;
#pragma unroll
        for (int k = 0; k < 8; ++k) {
            unsigned short s0 = f2bf(fmaf(acc[k],     dvn, bias[c16 + k]));
            unsigned short s1 = f2bf(fmaf(acc[k + 8], dvn, bias[c16 + 8 + k]));
            o0[k] = (short)((s0 & 0x8000u) ? 0 : s0);   // relu folded
            o1[k] = (short)((s1 & 0x8000u) ? 0 : s1);
        }
        const unsigned int bofs = (unsigned)(lrow * (FIN * 2) + c16 * 2);
        const unsigned int msk  = (unsigned)((lrow & 7) << 4);
        *(short8*)((char*)lag + (bofs ^ msk)) = o0;
        *(short8*)((char*)lag + ((bofs + 16) ^ msk)) = o1;
    }
    __syncthreads();

    // ---- phase 2: GEMM m-tiles of this block's rows from LDS (swizzled reads) ----
    const int lane = t & 63, wv = t >> 6;
    const int m16 = lane & 15, quad = lane >> 4;
    const int tile = wv / WPT, ch = wv - tile * WPT;
    const int colb = ch * NT * 16;

    short8 bfrag[NT][KS];
#pragma unroll
    for (int nt = 0; nt < NT; ++nt) {
        const unsigned short* wcol = Wbt + (size_t)(colb + nt * 16 + m16) * FIN + quad * 8;
#pragma unroll
        for (int ks = 0; ks < KS; ++ks)
            bfrag[nt][ks] = *(const short8*)(wcol + ks * 32);
    }
    short8 afrag[KS];
    const int arow = tile * 16 + m16;
    const unsigned int abase = (unsigned)(arow * (FIN * 2) + quad * 16);
    const unsigned int am    = (unsigned)((arow & 7) << 4);
#pragma unroll
    for (int ks = 0; ks < KS; ++ks)
        afrag[ks] = *(const short8*)((char*)lag + ((abase + (unsigned)(ks * 64)) ^ am));

    f32x4 acc2[NT];
#pragma unroll
    for (int nt = 0; nt < NT; ++nt) acc2[nt] = (f32x4){0.f, 0.f, 0.f, 0.f};
#pragma unroll
    for (int nt = 0; nt < NT; ++nt)
#pragma unroll
        for (int ks = 0; ks < KS; ++ks)
            acc2[nt] = __builtin_amdgcn_mfma_f32_16x16x32_bf16(
                __builtin_bit_cast(bf16x8, afrag[ks]),
                __builtin_bit_cast(bf16x8, bfrag[nt][ks]), acc2[nt], 0, 0, 0);

    const int rbase = nb * NPB + tile * 16 + quad * 4;
    float dv[4];
#pragma unroll
    for (int r = 0; r < 4; ++r) dv[r] = dinv[min(rbase + r, N - 1)];
#pragma unroll
    for (int nt = 0; nt < NT; ++nt) {
        const int col = colb + nt * 16 + m16;
#pragma unroll
        for (int r = 0; r < 4; ++r) {
            int orow = rbase + r;
            if (orow < N) {
                float v = acc2[nt][r] * dv[r];
                if (OUT_FP8)
                    ((unsigned char*)out)[(size_t)orow * FOUT + col] = f2fp8(v);
                else
                    ((unsigned short*)out)[(size_t)orow * FOUT + col] = f2bf(v);
            }
        }
    }
}

// ---------------- layer-3 agg (bf16 gather) + pool fused: per-block graph partials ----------------
// Nodes are graph-contiguous (batch sorted), so a 64-node block spans <=64 graphs.
// Accumulate agg3 rows into LDS partials, flush once per (graph,col) via atomics.
__global__ __launch_bounds__(256) void agg3pool_kernel(const int* __restrict__ rowptr,
                                                       const int* __restrict__ csr_src,
                                                       const unsigned short* __restrict__ hs,
                                                       const float* __restrict__ dinv,
                                                       const float* __restrict__ b,
                                                       const int* __restrict__ batch,
                                                       float* __restrict__ pooled, int N) {
    constexpr int F = 32, TPN = 4, NPB = 64;
    __shared__ float part[NPB + 2][32];
    __shared__ int gmin_sh, gmax_sh;
    const int base = blockIdx.x * NPB;
    const int n = base + threadIdx.x / TPN;
    const int c8 = (threadIdx.x % TPN) * 8;
    if (threadIdx.x == 0) gmin_sh = batch[min(base, N - 1)];
    if (threadIdx.x == 1) gmax_sh = batch[min(base + NPB - 1, N - 1)];
    for (int i = threadIdx.x; i < (NPB + 2) * 32; i += 256) ((float*)part)[i] = 0.f;
    __syncthreads();
    const int gmin = gmin_sh;
    if (n < N) {
        int row = rowptr[n], end = rowptr[n + 1];
        float acc[8];
        {
            short8 h = *(const short8*)(hs + (size_t)n * F + c8);   // self term
#pragma unroll
            for (int j = 0; j < 8; ++j) acc[j] = bf2f((unsigned short)h[j]);
        }
        int j = row;
        for (; j + 4 <= end; j += 4) {
            int s0 = csr_src[j], s1 = csr_src[j + 1], s2 = csr_src[j + 2], s3 = csr_src[j + 3];
            short8 h0 = *(const short8*)(hs + (size_t)s0 * F + c8);
            short8 h1 = *(const short8*)(hs + (size_t)s1 * F + c8);
            short8 h2 = *(const short8*)(hs + (size_t)s2 * F + c8);
            short8 h3 = *(const short8*)(hs + (size_t)s3 * F + c8);
#pragma unroll
            for (int k = 0; k < 8; ++k)
                acc[k] += (bf2f((unsigned short)h0[k]) + bf2f((unsigned short)h1[k])) +
                          (bf2f((unsigned short)h2[k]) + bf2f((unsigned short)h3[k]));
        }
        for (; j < end; ++j) {
            int s = csr_src[j];
            short8 h = *(const short8*)(hs + (size_t)s * F + c8);
#pragma unroll
            for (int k = 0; k < 8; ++k) acc[k] += bf2f((unsigned short)h[k]);
        }
        float c = dinv[n];
        int slot = batch[n] - gmin;
#pragma unroll
        for (int k = 0; k < 8; ++k)
            atomicAdd(&part[slot][c8 + k], fmaf(acc[k], c, b[c8 + k]));
    }
    __syncthreads();
    const int gspan = gmax_sh - gmin + 1;
    for (int i = threadIdx.x; i < gspan * 32; i += 256) {
        float v = part[i >> 5][i & 31];
        if (v != 0.f) atomicAdd(&pooled[(size_t)(gmin + (i >> 5)) * 32 + (i & 31)], v);
    }
}

// ---------------- epilogue: mean, logits, sigmoid, BCE ----------------
__global__ __launch_bounds__(256) void final_kernel(const float* __restrict__ pooled,
                                                    const int* __restrict__ gstart,
                                                    const float* __restrict__ Wl,
                                                    const float* __restrict__ bl,
                                                    const int* __restrict__ targets,
                                                    float* __restrict__ out) {
    __shared__ float red[256];
    float lsum = 0.0f;
    for (int g = threadIdx.x; g < NG; g += 256) {
        float cntf = fmaxf((float)(gstart[g + 1] - gstart[g]), 1.0f);
        float acc = bl[0];
#pragma unroll
        for (int k = 0; k < 32; ++k)
            acc = fmaf(pooled[(size_t)g * 32 + k] / cntf, Wl[k], acc);
        out[g] = 1.0f / (1.0f + expf(-acc));
        float y = (float)targets[g];
        lsum += fmaxf(acc, 0.0f) - acc * y + log1pf(expf(-fabsf(acc)));
    }
    red[threadIdx.x] = lsum;
    __syncthreads();
    for (int s = 128; s > 0; s >>= 1) {
        if (threadIdx.x < s) red[threadIdx.x] += red[threadIdx.x + s];
        __syncthreads();
    }
    if (threadIdx.x == 0) out[NG] = red[0] / (float)NG;
}

extern "C" void kernel_launch(void* const* d_in, const int* in_sizes, int n_in,
                              void* d_out, int out_size, void* d_ws, size_t ws_size,
                              hipStream_t stream) {
    const float* x       = (const float*)d_in[0];
    const int*   ei      = (const int*)d_in[1];
    const int*   batch   = (const int*)d_in[2];
    const int*   targets = (const int*)d_in[3];
    const float* W1 = (const float*)d_in[4];
    const float* b1 = (const float*)d_in[5];
    const float* W2 = (const float*)d_in[6];
    const float* b2 = (const float*)d_in[7];
    const float* W3 = (const float*)d_in[8];
    const float* b3 = (const float*)d_in[9];
    const float* Wl = (const float*)d_in[10];
    const float* bl = (const float*)d_in[11];
    float* out = (float*)d_out;
    char*  ws  = (char*)d_ws;

    const int* src = ei;
    const int* dst = ei + NE;

    // workspace layout (byte offsets, 512B aligned) — total ~68.3 MB
    float*          dinv    = (float*)(ws);                    //    400,384 B
    int*            rowptr  = (int*)(ws + 400384);             //    400,384 B (NN+1)
    int*            csr_src = (int*)(ws + 800768);             //  6,400,512 B
    unsigned short* Wb1t    = (unsigned short*)(ws + 7201280); //     32,768 B (transposed)
    unsigned short* Wb2t    = (unsigned short*)(ws + 7234048); //     16,384 B (transposed)
    unsigned short* Wb3t    = (unsigned short*)(ws + 7250432); //      4,096 B (transposed)
    int*            gstart  = (int*)(ws + 7254528);            //      8,704 B (NG+1)
    unsigned char*  hsbuf   = (unsigned char*)(ws + 7263232);  // 12.8 MB fp8 hu / 6.4 MB bf16 hs3
    unsigned short* aggbuf  = (unsigned short*)(ws + 32863744);// fp8 hs2 [100K x 64]
    float*          pooled  = (float*)(ws + 58464256);         //    262,144 B (sums)
    int*            bdata   = (int*)(ws + 58726400);           //  9,609,216 B (391*6144*4)
    int*            gcnt    = (int*)(ws + 68335616);           //      2,048 B

    // ---- setup (w2bf + grange + gcnt zero + pooled zero) ----
    setup_kernel<<<370, 256, 0, stream>>>(W1, W2, W3, Wb1t, Wb2t, Wb3t, batch, gstart, gcnt, pooled);

    // ---- bin || gemm1a-unscaled (tiles [0, MT_SPLIT)) ----
    bin_gemm1_kernel<<<BINB + GA, 256, 0, stream>>>(src, dst, gcnt, bdata, x, Wb1t, hsbuf);

    // ---- csr2a+fill merged || gemm1b-unscaled (tiles [MT_SPLIT, MT_ALL)) ----
    csr2afill_gemm1_kernel<<<NBUK + GB, 256, 0, stream>>>(gcnt, bdata, dinv, rowptr, csr_src,
                                                          x, Wb1t, hsbuf);

    // ---- fused agg1+gemm2 (UNSCALED table: gathers dinv[src]) -> hs2 fp8[100K x 64] ----
    agg_gemm_kernel<128, 64, true, false><<<(NN + 31) / 32, 256, 0, stream>>>(
        rowptr, csr_src, hsbuf, dinv, b1, Wb2t, (void*)aggbuf, NN);

    // ---- fused agg2+gemm3 (SCALED table) -> hs3 bf16[100K x 32] ----
    agg_gemm_kernel<64, 32, false, true><<<(NN + 63) / 64, 256, 0, stream>>>(
        rowptr, csr_src, (const unsigned char*)aggbuf, dinv, b2, Wb3t, (void*)hsbuf, NN);

    // ---- layer 3 agg + pool fused (graph partials -> pooled sums) ----
    agg3pool_kernel<<<(NN + 63) / 64, 256, 0, stream>>>(rowptr, csr_src,
        (const unsigned short*)hsbuf, dinv, b3, batch, pooled, NN);

    // ---- epilogue (mean + logits + BCE) ----
    final_kernel<<<1, 256, 0, stream>>>(pooled, gstart, Wl, bl, targets, out);
}

// Round 9
// 290.527 us; speedup vs baseline: 1.2152x; 1.0153x over previous
//
#include <hip/hip_runtime.h>
#include <math.h>

#define NN 100000
#define NE 1600000
#define NG 2048
#define NBUK 391     // ceil(NN/256) dst-buckets, bucket = dst >> 8
#define SLOT 6144    // per-bucket capacity: mean 4096 + 32 sigma
#define CHUNK 8192   // edges per bin block
#define FILLB 391    // fill-path blocks in fused kernel
#define GEMMB 832    // gemm blocks (3328 waves, ~1.9 m-tiles/wave)

typedef __attribute__((ext_vector_type(8))) short short8;
typedef __attribute__((ext_vector_type(8))) __bf16 bf16x8;
typedef __attribute__((ext_vector_type(4))) float f32x4;
typedef __attribute__((ext_vector_type(2))) float f32x2;
typedef __attribute__((ext_vector_type(4))) unsigned int uint4_;

__device__ __forceinline__ unsigned short f2bf(float f) {       // RNE, finite inputs
    unsigned int u = __float_as_uint(f);
    return (unsigned short)((u + 0x7FFFu + ((u >> 16) & 1u)) >> 16);
}
__device__ __forceinline__ float bf2f(unsigned short s) {
    return __uint_as_float(((unsigned int)s) << 16);
}
__device__ __forceinline__ unsigned char f2fp8(float v) {       // HW cvt, e4m3fn
    int p = __builtin_amdgcn_cvt_pk_fp8_f32(v, v, 0, false);
    return (unsigned char)(p & 0xFF);
}
// R21: async global->LDS 16B (per-lane global addr, wave-uniform LDS base + lane*16)
__device__ __forceinline__ void glds16(const void* g, void* l) {
    __builtin_amdgcn_global_load_lds(
        (const __attribute__((address_space(1))) unsigned int*)g,
        (__attribute__((address_space(3))) unsigned int*)l, 16, 0, 0);
}

// ---------------- setup: w2bf (transposed) + grange + gcnt zero ----------------
__global__ __launch_bounds__(256) void setup_kernel(const float* __restrict__ W1,
                                                    const float* __restrict__ W2,
                                                    const float* __restrict__ W3,
                                                    unsigned short* __restrict__ Wb1t,
                                                    unsigned short* __restrict__ Wb2t,
                                                    unsigned short* __restrict__ Wb3t,
                                                    const int* __restrict__ batch,
                                                    int* __restrict__ gstart,
                                                    int* __restrict__ gcnt) {
    const int bid = blockIdx.x, t = threadIdx.x;
    if (bid < 104) {                                  // weight cvt+transpose (26624 elems)
        int i = bid * 256 + t;
        if (i < 16384) {                              // W1: 128x128
            int k = i >> 7, c = i & 127;
            Wb1t[c * 128 + k] = f2bf(W1[i]);
        } else if (i < 24576) {                       // W2: 128x64
            int j = i - 16384; int k = j >> 6, c = j & 63;
            Wb2t[c * 128 + k] = f2bf(W2[j]);
        } else if (i < 26624) {                       // W3: 64x32
            int j = i - 24576; int k = j >> 5, c = j & 31;
            Wb3t[c * 64 + k] = f2bf(W3[j]);
        }
    } else if (bid < 113) {                           // grange (batch sorted)
        int g = (bid - 104) * 256 + t;
        if (g > NG) return;
        if (g == NG) { gstart[g] = NN; return; }
        int lo = 0, hi = NN;
        while (lo < hi) { int mid = (lo + hi) >> 1; if (batch[mid] < g) lo = mid + 1; else hi = mid; }
        gstart[g] = lo;
    } else {                                          // zero gcnt (512 ints)
        gcnt[t] = 0; gcnt[t + 256] = 0;
    }
}

// ---------------- pass 1: bin edges by dst>>8, bucket-sorted block appends ----------------
__global__ __launch_bounds__(256) void bin_kernel(const int* __restrict__ src,
                                                  const int* __restrict__ dst,
                                                  int* __restrict__ gcnt,
                                                  int* __restrict__ bucket_data, int E) {
    __shared__ int cnt[512];                 // padded scan array
    __shared__ int offs[NBUK];
    __shared__ int cnt2[NBUK];
    __shared__ int gb[NBUK];
    __shared__ int packB[CHUNK];
    __shared__ unsigned short bktB[CHUNK];
    const int t = threadIdx.x;
    const int E0 = blockIdx.x * CHUNK;
    const int valid = min(CHUNK, E - E0);
    cnt[t] = 0; cnt[t + 256] = 0;
    for (int i = t; i < NBUK; i += 256) cnt2[i] = 0;
    __syncthreads();
    // A: count buckets
    for (int i = t; i < valid; i += 256)
        atomicAdd(&cnt[dst[E0 + i] >> 8], 1);
    __syncthreads();
    int o0 = cnt[t], o1 = cnt[t + 256];
    // B: inclusive Hillis-Steele scan over 512 (2 elems/thread)
    for (int off = 1; off < 512; off <<= 1) {
        int a0 = (t >= off) ? cnt[t - off] : 0;
        int a1 = (t + 256 >= off) ? cnt[t + 256 - off] : 0;
        __syncthreads();
        cnt[t] += a0; cnt[t + 256] += a1;
        __syncthreads();
    }
    if (t < NBUK)       { offs[t] = cnt[t] - o0;             gb[t] = o0 ? atomicAdd(&gcnt[t], o0) : 0; }
    if (t + 256 < NBUK) { offs[t + 256] = cnt[t + 256] - o1; gb[t + 256] = o1 ? atomicAdd(&gcnt[t + 256], o1) : 0; }
    __syncthreads();
    // C: re-read edges, place bucket-sorted into LDS
    for (int i = t; i < valid; i += 256) {
        int s = src[E0 + i], d = dst[E0 + i];
        int b = d >> 8;
        int pos = offs[b] + atomicAdd(&cnt2[b], 1);
        packB[pos] = (s << 8) | (d & 255);
        bktB[pos] = (unsigned short)b;
    }
    __syncthreads();
    // D: contiguous-per-bucket append to global streams
    for (int i = t; i < valid; i += 256) {
        int b = bktB[i];
        int idx = gb[b] + (i - offs[b]);
        if (idx < SLOT) bucket_data[b * SLOT + idx] = packB[i];
    }
}

// ---------------- pass 2a: per-bucket counts -> dinv + rowptr (base scanned inline) ----------------
__global__ __launch_bounds__(256) void csr2a_kernel(const int* __restrict__ gcnt,
                                                    const int* __restrict__ bucket_data,
                                                    float* __restrict__ dinv,
                                                    int* __restrict__ rowptr) {
    __shared__ int bs[512];
    __shared__ int counts[256];
    __shared__ int base_sh;
    const int t = threadIdx.x;
    const int b = blockIdx.x;
    // inline exclusive scan of min(gcnt,SLOT) over all buckets (redundant per block)
    bs[t] = (t < NBUK) ? min(gcnt[t], SLOT) : 0;
    bs[t + 256] = (t + 256 < NBUK) ? min(gcnt[t + 256], SLOT) : 0;
    counts[t] = 0;
    __syncthreads();
    for (int off = 1; off < 512; off <<= 1) {
        int a0 = (t >= off) ? bs[t - off] : 0;
        int a1 = (t + 256 >= off) ? bs[t + 256 - off] : 0;
        __syncthreads();
        bs[t] += a0; bs[t + 256] += a1;
        __syncthreads();
    }
    if (t == 0) base_sh = bs[b] - min(gcnt[b], SLOT);   // exclusive base
    __syncthreads();
    const int cb = min(gcnt[b], SLOT);
    const int* bd = bucket_data + b * SLOT;
    for (int i = t; i < cb; i += 256) atomicAdd(&counts[bd[i] & 255], 1);
    __syncthreads();
    int c = counts[t];
    for (int off = 1; off < 256; off <<= 1) {
        int a = (t >= off) ? counts[t - off] : 0;
        __syncthreads();
        counts[t] += a;
        __syncthreads();
    }
    int excl = counts[t] - c;
    int node = b * 256 + t;
    if (node < NN) {
        dinv[node] = rsqrtf((float)c + 1.0f);
        rowptr[node] = base_sh + excl;
    }
    if (b == NBUK - 1 && t == 0) rowptr[NN] = NE;
}

// ---------------- MFMA GEMM body (layer 1 only now) ----------------
// Layouts [m89-verified]: A: m=lane&15, k=quad*8+j ; B: n=lane&15, k=quad*8+j ;
//                         C/D: col=lane&15, row=quad*4+reg.
template<int FIN, int FOUT, bool RELU_IN, bool A_BF16, bool OUT_FP8>
__device__ __forceinline__ void gemm_body(const void* __restrict__ in_,
                                          const unsigned short* __restrict__ Wbt,
                                          const float* __restrict__ dinv,
                                          void* __restrict__ out,
                                          int N, int nwaves, int wid, int lane) {
    constexpr int NT = FOUT / 16;
    constexpr int KS = FIN / 32;
    const int m16  = lane & 15;
    const int quad = lane >> 4;
    const int koff = quad * 8;

    short8 bfrag[NT][KS];
#pragma unroll
    for (int nt = 0; nt < NT; ++nt) {
        const unsigned short* wcol = Wbt + (size_t)(m16 + nt * 16) * FIN + koff;
#pragma unroll
        for (int ks = 0; ks < KS; ++ks)
            bfrag[nt][ks] = *(const short8*)(wcol + ks * 32);
    }

    const int MT = N / 16;                 // N == 100000 -> exact
    int mt = wid;
    if (mt >= MT) return;

    short8 curB[KS], nxtB[KS];
    f32x4  curF[KS][2], nxtF[KS][2];

    auto load_raw = [&](int m, short8* rb, f32x4 (*rf)[2]) {
        const int row = m * 16 + m16;
        if (A_BF16) {
            const unsigned short* A = (const unsigned short*)in_ + (size_t)row * FIN + koff;
#pragma unroll
            for (int ks = 0; ks < KS; ++ks) rb[ks] = *(const short8*)(A + ks * 32);
        } else {
            const float* A = (const float*)in_ + (size_t)row * FIN + koff;
#pragma unroll
            for (int ks = 0; ks < KS; ++ks) {
                rf[ks][0] = *(const f32x4*)(A + ks * 32);
                rf[ks][1] = *(const f32x4*)(A + ks * 32 + 4);
            }
        }
    };

    load_raw(mt, curB, curF);
    while (true) {
        const int mtn = mt + nwaves;
        const bool have_next = (mtn < MT);
        if (have_next) load_raw(mtn, nxtB, nxtF);   // in flight across the MFMAs below

        short8 afrag[KS];
        if (A_BF16) {
#pragma unroll
            for (int ks = 0; ks < KS; ++ks) {
                short8 a = curB[ks];
                if (RELU_IN) {
#pragma unroll
                    for (int j = 0; j < 8; ++j)
                        a[j] = (short)(((unsigned short)a[j] & 0x8000u) ? 0 : (unsigned short)a[j]);
                }
                afrag[ks] = a;
            }
        } else {
#pragma unroll
            for (int ks = 0; ks < KS; ++ks) {
#pragma unroll
                for (int j = 0; j < 4; ++j) {
                    float a0 = curF[ks][0][j], a1 = curF[ks][1][j];
                    if (RELU_IN) { a0 = fmaxf(a0, 0.f); a1 = fmaxf(a1, 0.f); }
                    afrag[ks][j]     = (short)f2bf(a0);
                    afrag[ks][j + 4] = (short)f2bf(a1);
                }
            }
        }

        f32x4 acc[NT];
#pragma unroll
        for (int nt = 0; nt < NT; ++nt) acc[nt] = (f32x4){0.f, 0.f, 0.f, 0.f};
#pragma unroll
        for (int nt = 0; nt < NT; ++nt)
#pragma unroll
            for (int ks = 0; ks < KS; ++ks)
                acc[nt] = __builtin_amdgcn_mfma_f32_16x16x32_bf16(
                    __builtin_bit_cast(bf16x8, afrag[ks]),
                    __builtin_bit_cast(bf16x8, bfrag[nt][ks]), acc[nt], 0, 0, 0);

        float dv[4];
#pragma unroll
        for (int r = 0; r < 4; ++r) dv[r] = dinv[mt * 16 + quad * 4 + r];
#pragma unroll
        for (int nt = 0; nt < NT; ++nt) {
            const int col = m16 + nt * 16;
#pragma unroll
            for (int r = 0; r < 4; ++r) {
                int orow = mt * 16 + quad * 4 + r;
                float v = acc[nt][r] * dv[r];
                if (OUT_FP8)
                    ((unsigned char*)out)[(size_t)orow * FOUT + col] = f2fp8(v);
                else
                    ((unsigned short*)out)[(size_t)orow * FOUT + col] = f2bf(v);
            }
        }

        if (!have_next) break;
#pragma unroll
        for (int ks = 0; ks < KS; ++ks) {
            curB[ks] = nxtB[ks];
            curF[ks][0] = nxtF[ks][0];
            curF[ks][1] = nxtF[ks][1];
        }
        mt = mtn;
    }
}

// ---------------- fused: CSR fine-scatter (blocks 0..390) || gemm1 (rest) ----------------
__global__ __launch_bounds__(256, 2) void fill_gemm1_kernel(const int* __restrict__ gcnt,
                                                            const int* __restrict__ bucket_data,
                                                            const int* __restrict__ rowptr,
                                                            int* __restrict__ csr_src,
                                                            const float* __restrict__ x,
                                                            const unsigned short* __restrict__ Wb1t,
                                                            const float* __restrict__ dinv,
                                                            unsigned char* __restrict__ hs) {
    __shared__ int offs[256];
    __shared__ int cnt2[256];
    const int t = threadIdx.x;
    if (blockIdx.x < FILLB) {
        const int b = blockIdx.x;
        const int cb = min(gcnt[b], SLOT);
        const int* bd = bucket_data + b * SLOT;
        int node = b * 256 + t;
        offs[t] = (node < NN) ? rowptr[node] : 0;
        cnt2[t] = 0;
        __syncthreads();
        for (int i = t; i < cb; i += 256) {
            int p = bd[i];
            int local = p & 255;
            int pos = atomicAdd(&cnt2[local], 1);
            csr_src[offs[local] + pos] = p >> 8;   // p>=0, arith shift ok
        }
    } else {
        const int wid = ((blockIdx.x - FILLB) * 256 + t) >> 6;
        gemm_body<128, 128, false, false, true>(x, Wb1t, dinv, hs, NN, GEMMB * 4, wid, t & 63);
    }
}

// ---------------- fused agg(FIN fp8 gather) + gemm(FIN->FOUT) ----------------
// STAGED (R21, FIN=128 only): gather via global_load_lds double-buffered pipeline.
//   Per wave (8 nodes): group = 4 edges/node = 4 glds16 instrs (1KB each, per-lane
//   global addr = row segment, LDS linear). Counted s_waitcnt vmcnt(5) keeps the
//   next group's 4 loads + 1 csr prefetch in flight (never drains to 0 mid-loop).
//   Tests whether LDS-DMA bypasses the per-CU L1-MSHR cap (~30 misses) that pins
//   the VGPR-gather at 3.84 TB/s (R13 depth-null evidence). Summation order
//   identical to the register path -> bit-exact.
// Non-staged path: original register gather (agg2 control).
// LDS XOR swizzle on lag (byte ^= (row&7)<<4) fixes 16-way ds_read_b128 conflict.
template<int FIN, int FOUT, bool OUT_FP8, bool STAGED>
__global__ __launch_bounds__(256) void agg_gemm_kernel(const int* __restrict__ rowptr,
                                                       const int* __restrict__ csr_src,
                                                       const unsigned char* __restrict__ hs,
                                                       const float* __restrict__ dinv,
                                                       const float* __restrict__ bias,
                                                       const unsigned short* __restrict__ Wbt,
                                                       void* __restrict__ out, int N) {
    constexpr int TPN  = FIN / 16;          // lanes per node (16 fp8 = 16 B each)
    constexpr int NPB  = 256 / TPN;         // nodes per block (32 or 64)
    constexpr int NTILE = NPB / 16;         // 16-row m-tiles per block (2 or 4)
    constexpr int WPT  = 4 / NTILE;         // waves per tile (2 or 1)
    constexpr int NT   = FOUT / (16 * WPT); // col-tiles per wave (2 in both cases)
    constexpr int KS   = FIN / 32;
    __shared__ unsigned short lag[NPB * FIN];   // XOR-swizzled rows
    __shared__ char stg[STAGED ? 32768 : 16];   // 4 waves x 2 bufs x 4KB

    const int t = threadIdx.x;
    const int nb = blockIdx.x;
    const int n = nb * NPB + t / TPN;

    if constexpr (STAGED) {
        // FIN=128: TPN=8, NPB=32; NN % 32 == 0 -> n always < N, no guards.
        const int l = t & 63, wv2 = t >> 6;
        const int lanep = t & 7;             // 16B segment within row
        const int lrow  = t >> 3;            // node row in block (0..31)
        char* wbuf = stg + wv2 * 8192;       // wave-private staging (2 x 4KB)
        const uint4_* hp = (const uint4_*)hs;
        const int rp  = rowptr[n];
        const int deg = rowptr[n + 1] - rp;
        uint4_ su = hp[(size_t)n * 8 + lanep];          // self term (issued early)
        int md = deg;
        md = max(md, __shfl_xor(md, 8, 64));
        md = max(md, __shfl_xor(md, 16, 64));
        md = max(md, __shfl_xor(md, 32, 64));
        const int G = (md + 3) >> 2;          // wave-uniform group count
        const int dm1 = max(deg - 1, 0);
        const int lk = lanep & 3;

        float acc[16];
#pragma unroll
        for (int w = 0; w < 4; ++w) {
            f32x2 lo = __builtin_amdgcn_cvt_pk_f32_fp8(su[w], false);
            f32x2 hi = __builtin_amdgcn_cvt_pk_f32_fp8(su[w], true);
            acc[w * 4 + 0] = lo[0]; acc[w * 4 + 1] = lo[1];
            acc[w * 4 + 2] = hi[0]; acc[w * 4 + 3] = hi[1];
        }

        if (G > 0) {
            // prologue: indices for group 0, issue eload(1) BEFORE stage(0)
            int e_cur = csr_src[rp + min(lk, dm1)];
            int i0 = __shfl(e_cur, (l & 56) | 0, 64);
            int i1 = __shfl(e_cur, (l & 56) | 1, 64);
            int i2 = __shfl(e_cur, (l & 56) | 2, 64);
            int i3 = __shfl(e_cur, (l & 56) | 3, 64);
            int e_nxt = csr_src[rp + min(4 + lk, dm1)];
            glds16(hs + (size_t)i0 * FIN + lanep * 16, wbuf + 0 * 1024);
            glds16(hs + (size_t)i1 * FIN + lanep * 16, wbuf + 1 * 1024);
            glds16(hs + (size_t)i2 * FIN + lanep * 16, wbuf + 2 * 1024);
            glds16(hs + (size_t)i3 * FIN + lanep * 16, wbuf + 3 * 1024);

            for (int g = 0; g < G; ++g) {
                if (g + 1 < G) {
                    int j0 = __shfl(e_nxt, (l & 56) | 0, 64);
                    int j1 = __shfl(e_nxt, (l & 56) | 1, 64);
                    int j2 = __shfl(e_nxt, (l & 56) | 2, 64);
                    int j3 = __shfl(e_nxt, (l & 56) | 3, 64);
                    int e_fut = csr_src[rp + min((g + 2) * 4 + lk, dm1)];  // always issued
                    char* nbuf = wbuf + ((g + 1) & 1) * 4096;
                    glds16(hs + (size_t)j0 * FIN + lanep * 16, nbuf + 0 * 1024);
                    glds16(hs + (size_t)j1 * FIN + lanep * 16, nbuf + 1 * 1024);
                    glds16(hs + (size_t)j2 * FIN + lanep * 16, nbuf + 2 * 1024);
                    glds16(hs + (size_t)j3 * FIN + lanep * 16, nbuf + 3 * 1024);
                    // drains group g's 4 loads; keeps e_fut + stage(g+1) in flight
                    asm volatile("s_waitcnt vmcnt(5)" ::: "memory");
                    e_nxt = e_fut;
                } else {
                    asm volatile("s_waitcnt vmcnt(0)" ::: "memory");
                }
                const char* cb = wbuf + (g & 1) * 4096;
                const int rem = deg - g * 4;
                if (rem > 0) {
                    uint4_ u0 = *(const uint4_*)(cb + 0 * 1024 + l * 16);
                    uint4_ u1 = *(const uint4_*)(cb + 1 * 1024 + l * 16);
                    uint4_ u2 = *(const uint4_*)(cb + 2 * 1024 + l * 16);
                    uint4_ u3 = *(const uint4_*)(cb + 3 * 1024 + l * 16);
                    if (rem >= 4) {
#pragma unroll
                        for (int w = 0; w < 4; ++w) {
                            f32x2 a0 = __builtin_amdgcn_cvt_pk_f32_fp8(u0[w], false);
                            f32x2 b0 = __builtin_amdgcn_cvt_pk_f32_fp8(u0[w], true);
                            f32x2 a1 = __builtin_amdgcn_cvt_pk_f32_fp8(u1[w], false);
                            f32x2 b1 = __builtin_amdgcn_cvt_pk_f32_fp8(u1[w], true);
                            f32x2 a2 = __builtin_amdgcn_cvt_pk_f32_fp8(u2[w], false);
                            f32x2 b2 = __builtin_amdgcn_cvt_pk_f32_fp8(u2[w], true);
                            f32x2 a3 = __builtin_amdgcn_cvt_pk_f32_fp8(u3[w], false);
                            f32x2 b3 = __builtin_amdgcn_cvt_pk_f32_fp8(u3[w], true);
                            acc[w * 4 + 0] += (a0[0] + a1[0]) + (a2[0] + a3[0]);
                            acc[w * 4 + 1] += (a0[1] + a1[1]) + (a2[1] + a3[1]);
                            acc[w * 4 + 2] += (b0[0] + b1[0]) + (b2[0] + b3[0]);
                            acc[w * 4 + 3] += (b0[1] + b1[1]) + (b2[1] + b3[1]);
                        }
                    } else {
                        if (rem > 0) {
#pragma unroll
                            for (int w = 0; w < 4; ++w) {
                                f32x2 lo = __builtin_amdgcn_cvt_pk_f32_fp8(u0[w], false);
                                f32x2 hi = __builtin_amdgcn_cvt_pk_f32_fp8(u0[w], true);
                                acc[w * 4 + 0] += lo[0]; acc[w * 4 + 1] += lo[1];
                                acc[w * 4 + 2] += hi[0]; acc[w * 4 + 3] += hi[1];
                            }
                        }
                        if (rem > 1) {
#pragma unroll
                            for (int w = 0; w < 4; ++w) {
                                f32x2 lo = __builtin_amdgcn_cvt_pk_f32_fp8(u1[w], false);
                                f32x2 hi = __builtin_amdgcn_cvt_pk_f32_fp8(u1[w], true);
                                acc[w * 4 + 0] += lo[0]; acc[w * 4 + 1] += lo[1];
                                acc[w * 4 + 2] += hi[0]; acc[w * 4 + 3] += hi[1];
                            }
                        }
                        if (rem > 2) {
#pragma unroll
                            for (int w = 0; w < 4; ++w) {
                                f32x2 lo = __builtin_amdgcn_cvt_pk_f32_fp8(u2[w], false);
                                f32x2 hi = __builtin_amdgcn_cvt_pk_f32_fp8(u2[w], true);
                                acc[w * 4 + 0] += lo[0]; acc[w * 4 + 1] += lo[1];
                                acc[w * 4 + 2] += hi[0]; acc[w * 4 + 3] += hi[1];
                            }
                        }
                    }
                }
            }
        }
        // epilogue: scale+bias+relu -> swizzled LDS (same as register path)
        const int c16 = lanep * 16;
        float c = dinv[n];
        short8 o0, o1;
#pragma unroll
        for (int k = 0; k < 8; ++k) {
            unsigned short s0 = f2bf(fmaf(acc[k],     c, bias[c16 + k]));
            unsigned short s1 = f2bf(fmaf(acc[k + 8], c, bias[c16 + 8 + k]));
            o0[k] = (short)((s0 & 0x8000u) ? 0 : s0);
            o1[k] = (short)((s1 & 0x8000u) ? 0 : s1);
        }
        const unsigned int bofs = (unsigned)(lrow * (FIN * 2) + c16 * 2);
        const unsigned int msk  = (unsigned)((lrow & 7) << 4);
        *(short8*)((char*)lag + (bofs ^ msk)) = o0;
        *(short8*)((char*)lag + ((bofs + 16) ^ msk)) = o1;
    } else if (n < N) {
        // ---- original register-gather phase 1 (SCALED table) ----
        const uint4_* hp = (const uint4_*)hs;
        const int lanep = t % TPN;
        const int lrow  = t / TPN;
        const int rstride = FIN / 16;
        const int c16 = lanep * 16;
        int row = rowptr[n], end = rowptr[n + 1];
        float acc[16];
        {
            uint4_ u = hp[(size_t)n * rstride + lanep];   // self term
#pragma unroll
            for (int w = 0; w < 4; ++w) {
                f32x2 lo = __builtin_amdgcn_cvt_pk_f32_fp8(u[w], false);
                f32x2 hi = __builtin_amdgcn_cvt_pk_f32_fp8(u[w], true);
                acc[w * 4 + 0] = lo[0]; acc[w * 4 + 1] = lo[1];
                acc[w * 4 + 2] = hi[0]; acc[w * 4 + 3] = hi[1];
            }
        }
        int j = row;
        for (; j + 4 <= end; j += 4) {
            int s0 = csr_src[j], s1 = csr_src[j + 1], s2 = csr_src[j + 2], s3 = csr_src[j + 3];
            uint4_ u0 = hp[(size_t)s0 * rstride + lanep];
            uint4_ u1 = hp[(size_t)s1 * rstride + lanep];
            uint4_ u2 = hp[(size_t)s2 * rstride + lanep];
            uint4_ u3 = hp[(size_t)s3 * rstride + lanep];
#pragma unroll
            for (int w = 0; w < 4; ++w) {
                f32x2 a0 = __builtin_amdgcn_cvt_pk_f32_fp8(u0[w], false);
                f32x2 b0 = __builtin_amdgcn_cvt_pk_f32_fp8(u0[w], true);
                f32x2 a1 = __builtin_amdgcn_cvt_pk_f32_fp8(u1[w], false);
                f32x2 b1 = __builtin_amdgcn_cvt_pk_f32_fp8(u1[w], true);
                f32x2 a2 = __builtin_amdgcn_cvt_pk_f32_fp8(u2[w], false);
                f32x2 b2 = __builtin_amdgcn_cvt_pk_f32_fp8(u2[w], true);
                f32x2 a3 = __builtin_amdgcn_cvt_pk_f32_fp8(u3[w], false);
                f32x2 b3 = __builtin_amdgcn_cvt_pk_f32_fp8(u3[w], true);
                acc[w * 4 + 0] += (a0[0] + a1[0]) + (a2[0] + a3[0]);
                acc[w * 4 + 1] += (a0[1] + a1[1]) + (a2[1] + a3[1]);
                acc[w * 4 + 2] += (b0[0] + b1[0]) + (b2[0] + b3[0]);
                acc[w * 4 + 3] += (b0[1] + b1[1]) + (b2[1] + b3[1]);
            }
        }
        for (; j < end; ++j) {
            uint4_ u = hp[(size_t)csr_src[j] * rstride + lanep];
#pragma unroll
            for (int w = 0; w < 4; ++w) {
                f32x2 lo = __builtin_amdgcn_cvt_pk_f32_fp8(u[w], false);
                f32x2 hi = __builtin_amdgcn_cvt_pk_f32_fp8(u[w], true);
                acc[w * 4 + 0] += lo[0]; acc[w * 4 + 1] += lo[1];
                acc[w * 4 + 2] += hi[0]; acc[w * 4 + 3] += hi[1];
            }
        }
        float c = dinv[n];
        short8 o0, o1;
#pragma unroll
        for (int k = 0; k < 8; ++k) {
            unsigned short s0 = f2bf(fmaf(acc[k],     c, bias[c16 + k]));
            unsigned short s1 = f2bf(fmaf(acc[k + 8], c, bias[c16 + 8 + k]));
            o0[k] = (short)((s0 & 0x8000u) ? 0 : s0);   // relu folded
            o1[k] = (short)((s1 & 0x8000u) ? 0 : s1);
        }
        const unsigned int bofs = (unsigned)(lrow * (FIN * 2) + c16 * 2);
        const unsigned int msk  = (unsigned)((lrow & 7) << 4);
        *(short8*)((char*)lag + (bofs ^ msk)) = o0;
        *(short8*)((char*)lag + ((bofs + 16) ^ msk)) = o1;
    }
    __syncthreads();

    // ---- phase 2: GEMM m-tiles of this block's rows from LDS (swizzled reads) ----
    const int lane = t & 63, wv = t >> 6;
    const int m16 = lane & 15, quad = lane >> 4;
    const int tile = wv / WPT, ch = wv - tile * WPT;
    const int colb = ch * NT * 16;

    short8 bfrag[NT][KS];
#pragma unroll
    for (int nt = 0; nt < NT; ++nt) {
        const unsigned short* wcol = Wbt + (size_t)(colb + nt * 16 + m16) * FIN + quad * 8;
#pragma unroll
        for (int ks = 0; ks < KS; ++ks)
            bfrag[nt][ks] = *(const short8*)(wcol + ks * 32);
    }
    short8 afrag[KS];
    const int arow = tile * 16 + m16;
    const unsigned int abase = (unsigned)(arow * (FIN * 2) + quad * 16);
    const unsigned int am    = (unsigned)((arow & 7) << 4);
#pragma unroll
    for (int ks = 0; ks < KS; ++ks)
        afrag[ks] = *(const short8*)((char*)lag + ((abase + (unsigned)(ks * 64)) ^ am));

    f32x4 acc2[NT];
#pragma unroll
    for (int nt = 0; nt < NT; ++nt) acc2[nt] = (f32x4){0.f, 0.f, 0.f, 0.f};
#pragma unroll
    for (int nt = 0; nt < NT; ++nt)
#pragma unroll
        for (int ks = 0; ks < KS; ++ks)
            acc2[nt] = __builtin_amdgcn_mfma_f32_16x16x32_bf16(
                __builtin_bit_cast(bf16x8, afrag[ks]),
                __builtin_bit_cast(bf16x8, bfrag[nt][ks]), acc2[nt], 0, 0, 0);

    const int rbase = nb * NPB + tile * 16 + quad * 4;
    float dv[4];
#pragma unroll
    for (int r = 0; r < 4; ++r) dv[r] = dinv[min(rbase + r, N - 1)];
#pragma unroll
    for (int nt = 0; nt < NT; ++nt) {
        const int col = colb + nt * 16 + m16;
#pragma unroll
        for (int r = 0; r < 4; ++r) {
            int orow = rbase + r;
            if (orow < N) {
                float v = acc2[nt][r] * dv[r];
                if (OUT_FP8)
                    ((unsigned char*)out)[(size_t)orow * FOUT + col] = f2fp8(v);
                else
                    ((unsigned short*)out)[(size_t)orow * FOUT + col] = f2bf(v);
            }
        }
    }
}

// ---------------- bf16 gather-aggregate (layer 3): fp32 out for pooling ----------------
__global__ __launch_bounds__(256) void agg3_kernel(const int* __restrict__ rowptr,
                                                   const int* __restrict__ csr_src,
                                                   const unsigned short* __restrict__ hs,
                                                   const float* __restrict__ dinv,
                                                   const float* __restrict__ b,
                                                   float* __restrict__ aggout, int N) {
    constexpr int F = 32, TPN = 4, NPB = 64;
    int n = blockIdx.x * NPB + threadIdx.x / TPN;
    int c8 = (threadIdx.x % TPN) * 8;
    if (n >= N) return;
    int row = rowptr[n], end = rowptr[n + 1];
    float acc[8];
    {
        short8 h = *(const short8*)(hs + (size_t)n * F + c8);   // self term
#pragma unroll
        for (int j = 0; j < 8; ++j) acc[j] = bf2f((unsigned short)h[j]);
    }
    int j = row;
    for (; j + 4 <= end; j += 4) {
        int s0 = csr_src[j], s1 = csr_src[j + 1], s2 = csr_src[j + 2], s3 = csr_src[j + 3];
        short8 h0 = *(const short8*)(hs + (size_t)s0 * F + c8);
        short8 h1 = *(const short8*)(hs + (size_t)s1 * F + c8);
        short8 h2 = *(const short8*)(hs + (size_t)s2 * F + c8);
        short8 h3 = *(const short8*)(hs + (size_t)s3 * F + c8);
#pragma unroll
        for (int k = 0; k < 8; ++k)
            acc[k] += (bf2f((unsigned short)h0[k]) + bf2f((unsigned short)h1[k])) +
                      (bf2f((unsigned short)h2[k]) + bf2f((unsigned short)h3[k]));
    }
    for (; j < end; ++j) {
        int s = csr_src[j];
        short8 h = *(const short8*)(hs + (size_t)s * F + c8);
#pragma unroll
        for (int k = 0; k < 8; ++k) acc[k] += bf2f((unsigned short)h[k]);
    }
    float c = dinv[n];
    f32x4 o0, o1;
#pragma unroll
    for (int k = 0; k < 4; ++k) {
        o0[k] = fmaf(acc[k], c, b[c8 + k]);
        o1[k] = fmaf(acc[k + 4], c, b[c8 + k + 4]);
    }
    float* of = aggout + (size_t)n * F + c8;
    *(f32x4*)of = o0;
    *(f32x4*)(of + 4) = o1;
}

// ---------------- pool: pooled[g,:] = mean of h rows in [gstart[g], gstart[g+1]) ----------------
__global__ __launch_bounds__(256) void pool2_kernel(const float* __restrict__ h,
                                                    const int* __restrict__ gstart,
                                                    float* __restrict__ pooled) {
    __shared__ float sm[256];
    int g = blockIdx.x;
    int s = gstart[g], e = gstart[g + 1];
    int f = threadIdx.x & 31, slot = threadIdx.x >> 5;
    float acc = 0.f;
    for (int n = s + slot; n < e; n += 8) acc += h[(size_t)n * 32 + f];
    sm[threadIdx.x] = acc;
    __syncthreads();
    if (threadIdx.x < 128) sm[threadIdx.x] += sm[threadIdx.x + 128];
    __syncthreads();
    if (threadIdx.x < 64) sm[threadIdx.x] += sm[threadIdx.x + 64];
    __syncthreads();
    if (threadIdx.x < 32) {
        float v = sm[threadIdx.x] + sm[threadIdx.x + 32];
        float cntf = fmaxf((float)(e - s), 1.0f);
        pooled[(size_t)g * 32 + f] = v / cntf;
    }
}

// ---------------- epilogue: logits, sigmoid, BCE mean ----------------
__global__ __launch_bounds__(256) void final_kernel(const float* __restrict__ pooled,
                                                    const float* __restrict__ Wl,
                                                    const float* __restrict__ bl,
                                                    const int* __restrict__ targets,
                                                    float* __restrict__ out) {
    __shared__ float red[256];
    float lsum = 0.0f;
    for (int g = threadIdx.x; g < NG; g += 256) {
        float acc = bl[0];
#pragma unroll
        for (int k = 0; k < 32; ++k)
            acc = fmaf(pooled[(size_t)g * 32 + k], Wl[k], acc);
        out[g] = 1.0f / (1.0f + expf(-acc));
        float y = (float)targets[g];
        lsum += fmaxf(acc, 0.0f) - acc * y + log1pf(expf(-fabsf(acc)));
    }
    red[threadIdx.x] = lsum;
    __syncthreads();
    for (int s = 128; s > 0; s >>= 1) {
        if (threadIdx.x < s) red[threadIdx.x] += red[threadIdx.x + s];
        __syncthreads();
    }
    if (threadIdx.x == 0) out[NG] = red[0] / (float)NG;
}

extern "C" void kernel_launch(void* const* d_in, const int* in_sizes, int n_in,
                              void* d_out, int out_size, void* d_ws, size_t ws_size,
                              hipStream_t stream) {
    const float* x       = (const float*)d_in[0];
    const int*   ei      = (const int*)d_in[1];
    const int*   batch   = (const int*)d_in[2];
    const int*   targets = (const int*)d_in[3];
    const float* W1 = (const float*)d_in[4];
    const float* b1 = (const float*)d_in[5];
    const float* W2 = (const float*)d_in[6];
    const float* b2 = (const float*)d_in[7];
    const float* W3 = (const float*)d_in[8];
    const float* b3 = (const float*)d_in[9];
    const float* Wl = (const float*)d_in[10];
    const float* bl = (const float*)d_in[11];
    float* out = (float*)d_out;
    char*  ws  = (char*)d_ws;

    const int* src = ei;
    const int* dst = ei + NE;

    // workspace layout (byte offsets, 512B aligned) — total ~68.3 MB
    float*          dinv    = (float*)(ws);                    //    400,384 B
    int*            rowptr  = (int*)(ws + 400384);             //    400,384 B (NN+1)
    int*            csr_src = (int*)(ws + 800768);             //  6,400,512 B
    unsigned short* Wb1t    = (unsigned short*)(ws + 7201280); //     32,768 B (transposed)
    unsigned short* Wb2t    = (unsigned short*)(ws + 7234048); //     16,384 B (transposed)
    unsigned short* Wb3t    = (unsigned short*)(ws + 7250432); //      4,096 B (transposed)
    int*            gstart  = (int*)(ws + 7254528);            //      8,704 B (NG+1)
    unsigned char*  hsbuf   = (unsigned char*)(ws + 7263232);  // 25,600,512 B (fp8 / bf16 row-major)
    unsigned short* aggbuf  = (unsigned short*)(ws + 32863744);// 25,600,512 B (fp8 hs2 / fp32 agg3)
    float*          pooled  = (float*)(ws + 58464256);         //    262,144 B
    int*            bdata   = (int*)(ws + 58726400);           //  9,609,216 B (391*6144*4)
    int*            gcnt    = (int*)(ws + 68335616);           //      2,048 B

    // ---- setup (w2bf + grange + gcnt zero) ----
    setup_kernel<<<114, 256, 0, stream>>>(W1, W2, W3, Wb1t, Wb2t, Wb3t, batch, gstart, gcnt);

    // ---- CSR build ----
    bin_kernel<<<(NE + CHUNK - 1) / CHUNK, 256, 0, stream>>>(src, dst, gcnt, bdata, NE);
    csr2a_kernel<<<NBUK, 256, 0, stream>>>(gcnt, bdata, dinv, rowptr);

    // ---- layer 1: CSR scatter || gemm1 (fused) ----
    fill_gemm1_kernel<<<FILLB + GEMMB, 256, 0, stream>>>(gcnt, bdata, rowptr, csr_src,
                                                         x, Wb1t, dinv, hsbuf);

    // ---- fused agg1+gemm2 (STAGED global_load_lds gather) -> hs2 fp8[100K x 64] ----
    agg_gemm_kernel<128, 64, true, true><<<(NN + 31) / 32, 256, 0, stream>>>(
        rowptr, csr_src, hsbuf, dinv, b1, Wb2t, (void*)aggbuf, NN);

    // ---- fused agg2+gemm3 (register gather, control) -> hs3 bf16[100K x 32] ----
    agg_gemm_kernel<64, 32, false, false><<<(NN + 63) / 64, 256, 0, stream>>>(
        rowptr, csr_src, (const unsigned char*)aggbuf, dinv, b2, Wb3t, (void*)hsbuf, NN);

    // ---- layer 3 agg (bf16 in, fp32 out); pool ----
    agg3_kernel<<<(NN + 63) / 64, 256, 0, stream>>>(rowptr, csr_src,
        (const unsigned short*)hsbuf, dinv, b3, (float*)aggbuf, NN);
    pool2_kernel<<<NG, 256, 0, stream>>>((const float*)aggbuf, gstart, pooled);

    // ---- epilogue ----
    final_kernel<<<1, 256, 0, stream>>>(pooled, Wl, bl, targets, out);
}